// Round 1
// baseline (13913.640 us; speedup 1.0000x reference)
//
#include <hip/hip_runtime.h>
#include <hip/hip_bf16.h>
#include <math.h>

#define NB     128
#define RESX   28
#define DIMC   192
#define NHEADS 6
#define WSZ    7
#define HD     32
#define NTOK   49
#define SCALE  0.17677669529663687f   // 32^-0.5
#define TOK28  (NB*RESX*RESX)         // 100352

__device__ __forceinline__ float gelu_f(float x){
    return 0.5f * x * (1.0f + erff(x * 0.70710678118654752f));
}
__device__ __forceinline__ float dot4(float4 a, float4 b){
    return a.x*b.x + a.y*b.y + a.z*b.z + a.w*b.w;
}

// ---------------- LayerNorm: one wave per token (4 tokens / 256-thread block)
__global__ __launch_bounds__(256) void ln_kernel(const float* __restrict__ x,
        const float* __restrict__ g, const float* __restrict__ be,
        float* __restrict__ out)
{
    int wid = threadIdx.x >> 6, lane = threadIdx.x & 63;
    size_t tok = (size_t)blockIdx.x * 4 + wid;
    const float* xr = x + tok * DIMC;
    float v0 = xr[lane], v1 = xr[lane + 64], v2 = xr[lane + 128];
    float s  = v0 + v1 + v2;
    float sq = v0*v0 + v1*v1 + v2*v2;
    #pragma unroll
    for (int o = 32; o > 0; o >>= 1){ s += __shfl_xor(s, o); sq += __shfl_xor(sq, o); }
    float mean = s * (1.0f/DIMC);
    float var  = sq * (1.0f/DIMC) - mean*mean;
    float rstd = rsqrtf(var + 1e-5f);
    float* orow = out + tok * DIMC;
    orow[lane]     = (v0-mean)*rstd*g[lane]     + be[lane];
    orow[lane+64]  = (v1-mean)*rstd*g[lane+64]  + be[lane+64];
    orow[lane+128] = (v2-mean)*rstd*g[lane+128] + be[lane+128];
}

// ---------------- depthwise 3x3 (NHWC) + exact GELU
__global__ void dw_gelu_kernel(const float* __restrict__ x, const float* __restrict__ dw,
                               float* __restrict__ y, int H, int W)
{
    int p = blockIdx.x;            // b*H*W + h*W + w
    int c = threadIdx.x;           // 0..191
    int w = p % W; int h = (p / W) % H; int b = p / (W*H);
    const float* base = x + (size_t)b*H*W*DIMC;
    float acc = 0.f;
    #pragma unroll
    for (int kh = 0; kh < 3; ++kh){
        int hh = h + kh - 1; if (hh < 0 || hh >= H) continue;
        #pragma unroll
        for (int kw = 0; kw < 3; ++kw){
            int ww = w + kw - 1; if (ww < 0 || ww >= W) continue;
            acc += base[((size_t)hh*W + ww)*DIMC + c] * dw[c*9 + kh*3 + kw];
        }
    }
    y[(size_t)p*DIMC + c] = gelu_f(acc);
}

// ---------------- SE: global average pool over HW
__global__ void se_reduce_kernel(const float* __restrict__ y, float* __restrict__ s0, int HW)
{
    int b = blockIdx.x; int c = threadIdx.x;
    const float* base = y + (size_t)b*HW*DIMC + c;
    float acc = 0.f;
    for (int p = 0; p < HW; ++p) acc += base[(size_t)p*DIMC];
    s0[b*DIMC + c] = acc / (float)HW;
}

// ---------------- SE: 192 -> gelu(48) -> sigmoid(192)
__global__ void se_mlp_kernel(const float* __restrict__ s0, const float* __restrict__ w1,
                              const float* __restrict__ w2, float* __restrict__ s)
{
    __shared__ float sl[DIMC];
    __shared__ float mid[48];
    int b = blockIdx.x; int t = threadIdx.x;
    sl[t] = s0[b*DIMC + t];
    __syncthreads();
    if (t < 48){
        float acc = 0.f;
        for (int c = 0; c < DIMC; ++c) acc += sl[c] * w1[t*DIMC + c];
        mid[t] = gelu_f(acc);
    }
    __syncthreads();
    float acc = 0.f;
    #pragma unroll 8
    for (int j = 0; j < 48; ++j) acc += mid[j] * w2[t*48 + j];
    s[b*DIMC + t] = 1.0f / (1.0f + expf(-acc));
}

// ---------------- generic 192x192 per-token GEMM:
// out[p,c] = (res?res[p,c]:0) + (bias?bias[c]:0) + sum_i in[p,i]*(sv?sv[b,i]:1)*W[c,i]
// 16 tokens/block, thread owns (c, token-octet) -> weight row read once per 8 tokens
__global__ __launch_bounds__(256) void gemm192_kernel(
    const float* __restrict__ in, const float* __restrict__ W,
    const float* __restrict__ bias, const float* __restrict__ res,
    const float* __restrict__ sv, int HW, float* __restrict__ out)
{
    __shared__ __align__(16) float xt[16*DIMC];
    int p0 = blockIdx.x * 16;
    int tid = threadIdx.x;
    if (sv){
        for (int i = tid; i < 16*DIMC; i += 256){
            int t = i / DIMC, c = i - t*DIMC;
            int p = p0 + t;
            xt[i] = in[(size_t)p*DIMC + c] * sv[(p/HW)*DIMC + c];
        }
    } else {
        for (int i = tid; i < 16*DIMC; i += 256)
            xt[i] = in[(size_t)p0*DIMC + i];
    }
    __syncthreads();
    for (int task = tid; task < 384; task += 256){
        int oct = task / 192, c = task - oct*192;
        const float4* wr4 = (const float4*)(W + (size_t)c*DIMC);
        float bb = bias ? bias[c] : 0.f;
        float acc[8];
        #pragma unroll
        for (int j = 0; j < 8; ++j) acc[j] = bb;
        const float* xb = xt + oct*8*DIMC;
        for (int k4 = 0; k4 < DIMC/4; ++k4){
            float4 w4 = wr4[k4];
            #pragma unroll
            for (int j = 0; j < 8; ++j){
                float4 a = ((const float4*)(xb + j*DIMC))[k4];
                acc[j] += dot4(a, w4);
            }
        }
        #pragma unroll
        for (int j = 0; j < 8; ++j){
            size_t o = (size_t)(p0 + oct*8 + j)*DIMC + c;
            out[o] = (res ? res[o] : 0.f) + acc[j];
        }
    }
}

// ---------------- maxpool 3x3 stride 2 pad 1 (NHWC)
__global__ void maxpool_kernel(const float* __restrict__ x, float* __restrict__ out,
                               int H, int W)
{
    int H2 = H >> 1, W2 = W >> 1;
    int p = blockIdx.x;            // b*H2*W2 + h2*W2 + w2
    int c = threadIdx.x;
    int w2 = p % W2; int h2 = (p / W2) % H2; int b = p / (W2*H2);
    float m = -INFINITY;
    #pragma unroll
    for (int dh = -1; dh <= 1; ++dh){
        int h = 2*h2 + dh; if (h < 0 || h >= H) continue;
        #pragma unroll
        for (int dw = -1; dw <= 1; ++dw){
            int w = 2*w2 + dw; if (w < 0 || w >= W) continue;
            m = fmaxf(m, x[(((size_t)b*H + h)*W + w)*DIMC + c]);
        }
    }
    out[(size_t)p*DIMC + c] = m;
}

// ---------------- fused window attention (qkv + bias + softmax + o), in-place xln -> O
__global__ __launch_bounds__(256) void attn_kernel(
    float* __restrict__ xio, const float* __restrict__ qg,
    const float* __restrict__ qkvw, const float* __restrict__ qkvb,
    const float* __restrict__ rpb, int isglobal)
{
    __shared__ __align__(16) float xt[NTOK*DIMC];   // 37632 B
    __shared__ __align__(16) float qs[NTOK*HD];     // 6272 B (q, later reused for v)
    __shared__ __align__(16) float kts[HD*NTOK];    // 6272 B (k transposed)
    __shared__ __align__(16) float sc[NTOK*NTOK];   // 9604 B
    int blk = blockIdx.x;
    int b = blk >> 4, win = blk & 15;
    int wr = win >> 2, wc = win & 3;
    int tid = threadIdx.x;
    for (int i = tid; i < NTOK*DIMC; i += 256){
        int t = i / DIMC, c = i - t*DIMC;
        int h = wr*WSZ + t/WSZ, w = wc*WSZ + (t - (t/WSZ)*WSZ);
        xt[i] = xio[(((size_t)b*RESX + h)*RESX + w)*DIMC + c];
    }
    __syncthreads();
    for (int hd = 0; hd < NHEADS; ++hd){
        // ---- q and k^T
        for (int i = tid; i < 2*NTOK*HD; i += 256){
            int which = i / (NTOK*HD);           // 0=q, 1=k
            int r = i - which*(NTOK*HD);
            int t = r / HD, d = r - t*HD;
            float acc;
            if (which == 0 && isglobal){
                acc = qg[((size_t)b*NTOK + t)*DIMC + hd*HD + d] * SCALE;
            } else {
                int f = (which == 0) ? (hd*HD + d)
                                     : ((isglobal ? 0 : DIMC) + hd*HD + d);
                float a = qkvb[f];
                const float4* wr4 = (const float4*)(qkvw + (size_t)f*DIMC);
                const float4* xr4 = (const float4*)(xt + t*DIMC);
                #pragma unroll 4
                for (int k4 = 0; k4 < DIMC/4; ++k4) a += dot4(xr4[k4], wr4[k4]);
                acc = (which == 0) ? a * SCALE : a;
            }
            if (which == 0) qs[t*HD + d] = acc;
            else            kts[d*NTOK + t] = acc;
        }
        __syncthreads();
        // ---- scores + relative position bias
        for (int i = tid; i < NTOK*NTOK; i += 256){
            int ti = i / NTOK, tj = i - ti*NTOK;
            const float* qrow = qs + ti*HD;
            float acc = 0.f;
            #pragma unroll 8
            for (int d = 0; d < HD; ++d) acc += qrow[d] * kts[d*NTOK + tj];
            int ri = ti/WSZ, ci = ti - ri*WSZ;
            int rj = tj/WSZ, cj = tj - rj*WSZ;
            acc += rpb[((ri - rj + 6)*13 + (ci - cj + 6))*NHEADS + hd];
            sc[i] = acc;
        }
        __syncthreads();
        // ---- softmax per row
        if (tid < NTOK){
            float* row = sc + tid*NTOK;
            float m = -INFINITY;
            for (int j = 0; j < NTOK; ++j) m = fmaxf(m, row[j]);
            float ssum = 0.f;
            for (int j = 0; j < NTOK; ++j){ float e = __expf(row[j] - m); row[j] = e; ssum += e; }
            float inv = 1.0f / ssum;
            for (int j = 0; j < NTOK; ++j) row[j] *= inv;
        }
        __syncthreads();
        // ---- v (reuse qs)
        for (int i = tid; i < NTOK*HD; i += 256){
            int t = i / HD, d = i - t*HD;
            int f = (isglobal ? DIMC : 2*DIMC) + hd*HD + d;
            float a = qkvb[f];
            const float4* wr4 = (const float4*)(qkvw + (size_t)f*DIMC);
            const float4* xr4 = (const float4*)(xt + t*DIMC);
            #pragma unroll 4
            for (int k4 = 0; k4 < DIMC/4; ++k4) a += dot4(xr4[k4], wr4[k4]);
            qs[i] = a;
        }
        __syncthreads();
        // ---- o = P @ v, write back over xln (win_rev applied via pixel indexing)
        for (int i = tid; i < NTOK*HD; i += 256){
            int t = i / HD, d = i - t*HD;
            const float* prow = sc + t*NTOK;
            float acc = 0.f;
            #pragma unroll 7
            for (int m2 = 0; m2 < NTOK; ++m2) acc += prow[m2] * qs[m2*HD + d];
            int h = wr*WSZ + t/WSZ, w = wc*WSZ + (t - (t/WSZ)*WSZ);
            xio[(((size_t)b*RESX + h)*RESX + w)*DIMC + hd*HD + d] = acc;
        }
        __syncthreads();
    }
}

// ---------------- fused MLP: x += gelu(ln_x @ W1^T + b1) @ W2^T + b2 ; 16 tokens/block
__global__ __launch_bounds__(256) void mlp_kernel(
    const float* __restrict__ xln,
    const float* __restrict__ w1, const float* __restrict__ b1,
    const float* __restrict__ w2, const float* __restrict__ b2,
    float* __restrict__ xout)
{
    __shared__ __align__(16) float xt[16*DIMC];   // 12288 B
    __shared__ __align__(16) float h1[16*768];    // 49152 B
    int t0 = blockIdx.x * 16;
    int tid = threadIdx.x;
    for (int i = tid; i < 16*DIMC; i += 256)
        xt[i] = xln[(size_t)t0*DIMC + i];
    __syncthreads();
    // fc1 + gelu: tasks (octet, f) = 2*768
    for (int task = tid; task < 1536; task += 256){
        int oct = task / 768, f = task - oct*768;
        const float4* wr4 = (const float4*)(w1 + (size_t)f*DIMC);
        float bb = b1[f];
        float acc[8];
        #pragma unroll
        for (int j = 0; j < 8; ++j) acc[j] = bb;
        const float* xb = xt + oct*8*DIMC;
        for (int k4 = 0; k4 < DIMC/4; ++k4){
            float4 w4 = wr4[k4];
            #pragma unroll
            for (int j = 0; j < 8; ++j){
                float4 a = ((const float4*)(xb + j*DIMC))[k4];
                acc[j] += dot4(a, w4);
            }
        }
        #pragma unroll
        for (int j = 0; j < 8; ++j) h1[(oct*8 + j)*768 + f] = gelu_f(acc[j]);
    }
    __syncthreads();
    // fc2 + residual: tasks (octet, c) = 2*192
    for (int task = tid; task < 384; task += 256){
        int oct = task / 192, c = task - oct*192;
        const float4* wr4 = (const float4*)(w2 + (size_t)c*768);
        float bb = b2[c];
        float acc[8];
        #pragma unroll
        for (int j = 0; j < 8; ++j) acc[j] = bb;
        const float* hb = h1 + oct*8*768;
        for (int k4 = 0; k4 < 768/4; ++k4){
            float4 w4 = wr4[k4];
            #pragma unroll
            for (int j = 0; j < 8; ++j){
                float4 a = ((const float4*)(hb + j*768))[k4];
                acc[j] += dot4(a, w4);
            }
        }
        #pragma unroll
        for (int j = 0; j < 8; ++j){
            size_t o = (size_t)(t0 + oct*8 + j)*DIMC + c;
            xout[o] += acc[j];
        }
    }
}

extern "C" void kernel_launch(void* const* d_in, const int* in_sizes, int n_in,
                              void* d_out, int out_size, void* d_ws, size_t ws_size,
                              hipStream_t stream)
{
    (void)in_sizes; (void)n_in; (void)out_size;
    const float* x = (const float*)d_in[0];
    const float* fe_dw[2]  = {(const float*)d_in[1], (const float*)d_in[5]};
    const float* fe_se1[2] = {(const float*)d_in[2], (const float*)d_in[6]};
    const float* fe_se2[2] = {(const float*)d_in[3], (const float*)d_in[7]};
    const float* fe_pw[2]  = {(const float*)d_in[4], (const float*)d_in[8]};
    const float* n1g[2]  = {(const float*)d_in[9],  (const float*)d_in[22]};
    const float* n1b[2]  = {(const float*)d_in[10], (const float*)d_in[23]};
    const float* qkvw[2] = {(const float*)d_in[11], (const float*)d_in[24]};
    const float* qkvb[2] = {(const float*)d_in[12], (const float*)d_in[25]};
    const float* rpb[2]  = {(const float*)d_in[13], (const float*)d_in[26]};
    const float* prjw[2] = {(const float*)d_in[14], (const float*)d_in[27]};
    const float* prjb[2] = {(const float*)d_in[15], (const float*)d_in[28]};
    const float* n2g[2]  = {(const float*)d_in[16], (const float*)d_in[29]};
    const float* n2b[2]  = {(const float*)d_in[17], (const float*)d_in[30]};
    const float* fc1w[2] = {(const float*)d_in[18], (const float*)d_in[31]};
    const float* fc1b[2] = {(const float*)d_in[19], (const float*)d_in[32]};
    const float* fc2w[2] = {(const float*)d_in[20], (const float*)d_in[33]};
    const float* fc2b[2] = {(const float*)d_in[21], (const float*)d_in[34]};

    float* out = (float*)d_out;
    float* ws = (float*)d_ws;
    const size_t n28 = (size_t)NB*RESX*RESX*DIMC;     // 19,267,584
    const size_t n14 = (size_t)NB*14*14*DIMC;         //  4,816,896
    const size_t n7  = (size_t)NB*7*7*DIMC;           //  1,204,224
    float* region0 = ws;
    float* x14 = region0 + n28;
    float* x7  = x14 + n14;
    float* s0  = x7 + n7;
    float* s1  = s0 + NB*DIMC;
    if (ws_size < (n28 + n14 + n7 + 2ull*NB*DIMC) * sizeof(float)) return;

    // ---- Phase A: GlobalQueryGen (from ORIGINAL x): 28 -> 14 -> 7
    for (int fe = 0; fe < 2; ++fe){
        int H = fe ? 14 : 28;
        int HW = H * H;
        const float* src = fe ? x14 : x;
        float* dst = fe ? x7 : x14;
        dw_gelu_kernel<<<NB*HW, DIMC, 0, stream>>>(src, fe_dw[fe], region0, H, H);
        se_reduce_kernel<<<NB, DIMC, 0, stream>>>(region0, s0, HW);
        se_mlp_kernel<<<NB, DIMC, 0, stream>>>(s0, fe_se1[fe], fe_se2[fe], s1);
        // in-place: region0 = src + pw(region0 * s1)
        gemm192_kernel<<<NB*HW/16, 256, 0, stream>>>(region0, fe_pw[fe], nullptr,
                                                     src, s1, HW, region0);
        maxpool_kernel<<<NB*(H/2)*(H/2), DIMC, 0, stream>>>(region0, dst, H, H);
    }

    // ---- Phase B: two attention blocks (0=local, 1=global query)
    for (int blk = 0; blk < 2; ++blk){
        const float* xin = blk ? (const float*)out : x;
        ln_kernel<<<TOK28/4, 256, 0, stream>>>(xin, n1g[blk], n1b[blk], region0);
        attn_kernel<<<NB*16, 256, 0, stream>>>(region0, blk ? x7 : nullptr,
                                               qkvw[blk], qkvb[blk], rpb[blk], blk);
        // out = xin + O @ proj^T + proj_b
        gemm192_kernel<<<TOK28/16, 256, 0, stream>>>(region0, prjw[blk], prjb[blk],
                                                     xin, nullptr, RESX*RESX, out);
        ln_kernel<<<TOK28/4, 256, 0, stream>>>(out, n2g[blk], n2b[blk], region0);
        mlp_kernel<<<TOK28/16, 256, 0, stream>>>(region0, fc1w[blk], fc1b[blk],
                                                 fc2w[blk], fc2b[blk], out);
    }
}

// Round 2
// 6896.029 us; speedup vs baseline: 2.0176x; 2.0176x over previous
//
#include <hip/hip_runtime.h>
#include <hip/hip_bf16.h>
#include <math.h>

#define NB     128
#define RESX   28
#define DIMC   192
#define NHEADS 6
#define WSZ    7
#define HD     32
#define NTOK   49
#define SCALE  0.17677669529663687f   // 32^-0.5
#define TOK28  (NB*RESX*RESX)         // 100352

__device__ __forceinline__ float gelu_f(float x){
    return 0.5f * x * (1.0f + erff(x * 0.70710678118654752f));
}
__device__ __forceinline__ float dot4(float4 a, float4 b){
    return a.x*b.x + a.y*b.y + a.z*b.z + a.w*b.w;
}

// ---------------- LayerNorm: one wave per token (4 tokens / 256-thread block)
__global__ __launch_bounds__(256) void ln_kernel(const float* __restrict__ x,
        const float* __restrict__ g, const float* __restrict__ be,
        float* __restrict__ out)
{
    int wid = threadIdx.x >> 6, lane = threadIdx.x & 63;
    size_t tok = (size_t)blockIdx.x * 4 + wid;
    const float* xr = x + tok * DIMC;
    float v0 = xr[lane], v1 = xr[lane + 64], v2 = xr[lane + 128];
    float s  = v0 + v1 + v2;
    float sq = v0*v0 + v1*v1 + v2*v2;
    #pragma unroll
    for (int o = 32; o > 0; o >>= 1){ s += __shfl_xor(s, o); sq += __shfl_xor(sq, o); }
    float mean = s * (1.0f/DIMC);
    float var  = sq * (1.0f/DIMC) - mean*mean;
    float rstd = rsqrtf(var + 1e-5f);
    float* orow = out + tok * DIMC;
    orow[lane]     = (v0-mean)*rstd*g[lane]     + be[lane];
    orow[lane+64]  = (v1-mean)*rstd*g[lane+64]  + be[lane+64];
    orow[lane+128] = (v2-mean)*rstd*g[lane+128] + be[lane+128];
}

// ---------------- depthwise 3x3 (NHWC) + exact GELU
__global__ void dw_gelu_kernel(const float* __restrict__ x, const float* __restrict__ dw,
                               float* __restrict__ y, int H, int W)
{
    int p = blockIdx.x;            // b*H*W + h*W + w
    int c = threadIdx.x;           // 0..191
    int w = p % W; int h = (p / W) % H; int b = p / (W*H);
    const float* base = x + (size_t)b*H*W*DIMC;
    float acc = 0.f;
    #pragma unroll
    for (int kh = 0; kh < 3; ++kh){
        int hh = h + kh - 1; if (hh < 0 || hh >= H) continue;
        #pragma unroll
        for (int kw = 0; kw < 3; ++kw){
            int ww = w + kw - 1; if (ww < 0 || ww >= W) continue;
            acc += base[((size_t)hh*W + ww)*DIMC + c] * dw[c*9 + kh*3 + kw];
        }
    }
    y[(size_t)p*DIMC + c] = gelu_f(acc);
}

// ---------------- SE: global average pool over HW
__global__ void se_reduce_kernel(const float* __restrict__ y, float* __restrict__ s0, int HW)
{
    int b = blockIdx.x; int c = threadIdx.x;
    const float* base = y + (size_t)b*HW*DIMC + c;
    float acc = 0.f;
    for (int p = 0; p < HW; ++p) acc += base[(size_t)p*DIMC];
    s0[b*DIMC + c] = acc / (float)HW;
}

// ---------------- SE: 192 -> gelu(48) -> sigmoid(192)
__global__ void se_mlp_kernel(const float* __restrict__ s0, const float* __restrict__ w1,
                              const float* __restrict__ w2, float* __restrict__ s)
{
    __shared__ float sl[DIMC];
    __shared__ float mid[48];
    int b = blockIdx.x; int t = threadIdx.x;
    sl[t] = s0[b*DIMC + t];
    __syncthreads();
    if (t < 48){
        float acc = 0.f;
        for (int c = 0; c < DIMC; ++c) acc += sl[c] * w1[t*DIMC + c];
        mid[t] = gelu_f(acc);
    }
    __syncthreads();
    float acc = 0.f;
    #pragma unroll 8
    for (int j = 0; j < 48; ++j) acc += mid[j] * w2[t*48 + j];
    s[b*DIMC + t] = 1.0f / (1.0f + expf(-acc));
}

// ---------------- generic 192x192 per-token GEMM (residual/scale variants)
__global__ __launch_bounds__(256) void gemm192_kernel(
    const float* __restrict__ in, const float* __restrict__ W,
    const float* __restrict__ bias, const float* __restrict__ res,
    const float* __restrict__ sv, int HW, float* __restrict__ out)
{
    __shared__ __align__(16) float xt[16*DIMC];
    int p0 = blockIdx.x * 16;
    int tid = threadIdx.x;
    if (sv){
        for (int i = tid; i < 16*DIMC; i += 256){
            int t = i / DIMC, c = i - t*DIMC;
            int p = p0 + t;
            xt[i] = in[(size_t)p*DIMC + c] * sv[(p/HW)*DIMC + c];
        }
    } else {
        for (int i = tid; i < 16*DIMC; i += 256)
            xt[i] = in[(size_t)p0*DIMC + i];
    }
    __syncthreads();
    for (int task = tid; task < 384; task += 256){
        int oct = task / 192, c = task - oct*192;
        const float4* wr4 = (const float4*)(W + (size_t)c*DIMC);
        float bb = bias ? bias[c] : 0.f;
        float acc[8];
        #pragma unroll
        for (int j = 0; j < 8; ++j) acc[j] = bb;
        const float* xb = xt + oct*8*DIMC;
        for (int k4 = 0; k4 < DIMC/4; ++k4){
            float4 w4 = wr4[k4];
            #pragma unroll
            for (int j = 0; j < 8; ++j){
                float4 a = ((const float4*)(xb + j*DIMC))[k4];
                acc[j] += dot4(a, w4);
            }
        }
        #pragma unroll
        for (int j = 0; j < 8; ++j){
            size_t o = (size_t)(p0 + oct*8 + j)*DIMC + c;
            out[o] = (res ? res[o] : 0.f) + acc[j];
        }
    }
}

// ---------------- qkv GEMM: out[p,f] = bias[f] + sum_i in[p,i]*W[f,i]  (F=576 or 384)
__global__ __launch_bounds__(256) void gemmF_kernel(
    const float* __restrict__ in, const float* __restrict__ W,
    const float* __restrict__ bias, float* __restrict__ out, int F)
{
    __shared__ __align__(16) float xt[16*DIMC];
    size_t p0 = (size_t)blockIdx.x * 16;
    int tid = threadIdx.x;
    for (int i = tid; i < 16*DIMC; i += 256)
        xt[i] = in[p0*DIMC + i];
    __syncthreads();
    for (int task = tid; task < 2*F; task += 256){
        int oct = task / F, f = task - (task/F)*F;
        const float4* wr4 = (const float4*)(W + (size_t)f*DIMC);
        float bb = bias[f];
        float acc[8];
        #pragma unroll
        for (int j = 0; j < 8; ++j) acc[j] = bb;
        const float* xb = xt + oct*8*DIMC;
        for (int k4 = 0; k4 < DIMC/4; ++k4){
            float4 w4 = wr4[k4];
            #pragma unroll
            for (int j = 0; j < 8; ++j){
                float4 a = ((const float4*)(xb + j*DIMC))[k4];
                acc[j] += dot4(a, w4);
            }
        }
        #pragma unroll
        for (int j = 0; j < 8; ++j)
            out[(p0 + oct*8 + j)*F + f] = acc[j];
    }
}

// ---------------- maxpool 3x3 stride 2 pad 1 (NHWC)
__global__ void maxpool_kernel(const float* __restrict__ x, float* __restrict__ out,
                               int H, int W)
{
    int H2 = H >> 1, W2 = W >> 1;
    int p = blockIdx.x;            // b*H2*W2 + h2*W2 + w2
    int c = threadIdx.x;
    int w2 = p % W2; int h2 = (p / W2) % H2; int b = p / (W2*H2);
    float m = -INFINITY;
    #pragma unroll
    for (int dh = -1; dh <= 1; ++dh){
        int h = 2*h2 + dh; if (h < 0 || h >= H) continue;
        #pragma unroll
        for (int dw = -1; dw <= 1; ++dw){
            int w = 2*w2 + dw; if (w < 0 || w >= W) continue;
            m = fmaxf(m, x[(((size_t)b*H + h)*W + w)*DIMC + c]);
        }
    }
    out[(size_t)p*DIMC + c] = m;
}

// ---------------- attention core: one block per (window, head)
// buf: [Ci*784, F] qkv rows (token-major, image order within chunk)
// O written in-place over xio (the xln buffer) at pixel+head-slice position.
__global__ __launch_bounds__(256) void attn_core_kernel(
    float* __restrict__ xio, const float* __restrict__ buf,
    const float* __restrict__ qg, const float* __restrict__ rpb,
    int F, int qoff, int koff, int voff, int b0)
{
    __shared__ float qs[NTOK*HD];     // 6272 B
    __shared__ float kts[HD*NTOK];    // 6272 B (k transposed)
    __shared__ float vs[NTOK*HD];     // 6272 B
    __shared__ float sc[NTOK*NTOK];   // 9604 B
    int blk = blockIdx.x;
    int hd  = blk % NHEADS;
    int wix = blk / NHEADS;
    int bloc = wix >> 4, win = wix & 15;
    int b = b0 + bloc;
    int wr = win >> 2, wc = win & 3;
    int tid = threadIdx.x;
    // ---- load q (scaled), k^T, v
    for (int i = tid; i < 3*NTOK*HD; i += 256){
        int which = i / (NTOK*HD), r = i - which*(NTOK*HD);
        int t = r >> 5, d = r & 31;
        int h = wr*WSZ + t/WSZ, w = wc*WSZ + t - (t/WSZ)*WSZ;
        size_t row = (size_t)bloc*784 + h*RESX + w;
        if (which == 0){
            float v = (qoff < 0)
                ? qg[((size_t)b*NTOK + t)*DIMC + hd*HD + d]
                : buf[row*F + qoff + hd*HD + d];
            qs[t*HD + d] = v * SCALE;
        } else if (which == 1){
            kts[d*NTOK + t] = buf[row*F + koff + hd*HD + d];
        } else {
            vs[t*HD + d] = buf[row*F + voff + hd*HD + d];
        }
    }
    __syncthreads();
    // ---- scores + relative position bias
    for (int i = tid; i < NTOK*NTOK; i += 256){
        int ti = i / NTOK, tj = i - (i/NTOK)*NTOK;
        float acc = 0.f;
        #pragma unroll 8
        for (int d = 0; d < HD; ++d) acc += qs[ti*HD + d] * kts[d*NTOK + tj];
        int ri = ti/WSZ, ci = ti - ri*WSZ;
        int rj = tj/WSZ, cj = tj - rj*WSZ;
        sc[i] = acc + rpb[((ri - rj + 6)*13 + (ci - cj + 6))*NHEADS + hd];
    }
    __syncthreads();
    // ---- softmax per row
    if (tid < NTOK){
        float* row = sc + tid*NTOK;
        float m = -INFINITY;
        for (int j = 0; j < NTOK; ++j) m = fmaxf(m, row[j]);
        float ssum = 0.f;
        for (int j = 0; j < NTOK; ++j){ float e = __expf(row[j] - m); row[j] = e; ssum += e; }
        float inv = 1.0f / ssum;
        for (int j = 0; j < NTOK; ++j) row[j] *= inv;
    }
    __syncthreads();
    // ---- o = P @ v, write to global (win_rev via pixel indexing)
    for (int i = tid; i < NTOK*HD; i += 256){
        int t = i >> 5, d = i & 31;
        const float* prow = sc + t*NTOK;
        float acc = 0.f;
        #pragma unroll 7
        for (int m2 = 0; m2 < NTOK; ++m2) acc += prow[m2] * vs[m2*HD + d];
        int h = wr*WSZ + t/WSZ, w = wc*WSZ + t - (t/WSZ)*WSZ;
        xio[(((size_t)b*RESX + h)*RESX + w)*DIMC + hd*HD + d] = acc;
    }
}

// ---------------- fused MLP: x += gelu(ln_x @ W1^T + b1) @ W2^T + b2 ; 16 tokens/block
__global__ __launch_bounds__(256) void mlp_kernel(
    const float* __restrict__ xln,
    const float* __restrict__ w1, const float* __restrict__ b1,
    const float* __restrict__ w2, const float* __restrict__ b2,
    float* __restrict__ xout)
{
    __shared__ __align__(16) float xt[16*DIMC];   // 12288 B
    __shared__ __align__(16) float h1[16*768];    // 49152 B
    int t0 = blockIdx.x * 16;
    int tid = threadIdx.x;
    for (int i = tid; i < 16*DIMC; i += 256)
        xt[i] = xln[(size_t)t0*DIMC + i];
    __syncthreads();
    for (int task = tid; task < 1536; task += 256){
        int oct = task / 768, f = task - oct*768;
        const float4* wr4 = (const float4*)(w1 + (size_t)f*DIMC);
        float bb = b1[f];
        float acc[8];
        #pragma unroll
        for (int j = 0; j < 8; ++j) acc[j] = bb;
        const float* xb = xt + oct*8*DIMC;
        for (int k4 = 0; k4 < DIMC/4; ++k4){
            float4 w4 = wr4[k4];
            #pragma unroll
            for (int j = 0; j < 8; ++j){
                float4 a = ((const float4*)(xb + j*DIMC))[k4];
                acc[j] += dot4(a, w4);
            }
        }
        #pragma unroll
        for (int j = 0; j < 8; ++j) h1[(oct*8 + j)*768 + f] = gelu_f(acc[j]);
    }
    __syncthreads();
    for (int task = tid; task < 384; task += 256){
        int oct = task / 192, c = task - oct*192;
        const float4* wr4 = (const float4*)(w2 + (size_t)c*768);
        float bb = b2[c];
        float acc[8];
        #pragma unroll
        for (int j = 0; j < 8; ++j) acc[j] = bb;
        const float* hb = h1 + oct*8*768;
        for (int k4 = 0; k4 < 768/4; ++k4){
            float4 w4 = wr4[k4];
            #pragma unroll
            for (int j = 0; j < 8; ++j){
                float4 a = ((const float4*)(hb + j*768))[k4];
                acc[j] += dot4(a, w4);
            }
        }
        #pragma unroll
        for (int j = 0; j < 8; ++j){
            size_t o = (size_t)(t0 + oct*8 + j)*DIMC + c;
            xout[o] += acc[j];
        }
    }
}

extern "C" void kernel_launch(void* const* d_in, const int* in_sizes, int n_in,
                              void* d_out, int out_size, void* d_ws, size_t ws_size,
                              hipStream_t stream)
{
    (void)in_sizes; (void)n_in; (void)out_size;
    const float* x = (const float*)d_in[0];
    const float* fe_dw[2]  = {(const float*)d_in[1], (const float*)d_in[5]};
    const float* fe_se1[2] = {(const float*)d_in[2], (const float*)d_in[6]};
    const float* fe_se2[2] = {(const float*)d_in[3], (const float*)d_in[7]};
    const float* fe_pw[2]  = {(const float*)d_in[4], (const float*)d_in[8]};
    const float* n1g[2]  = {(const float*)d_in[9],  (const float*)d_in[22]};
    const float* n1b[2]  = {(const float*)d_in[10], (const float*)d_in[23]};
    const float* qkvw[2] = {(const float*)d_in[11], (const float*)d_in[24]};
    const float* qkvb[2] = {(const float*)d_in[12], (const float*)d_in[25]};
    const float* rpb[2]  = {(const float*)d_in[13], (const float*)d_in[26]};
    const float* prjw[2] = {(const float*)d_in[14], (const float*)d_in[27]};
    const float* prjb[2] = {(const float*)d_in[15], (const float*)d_in[28]};
    const float* n2g[2]  = {(const float*)d_in[16], (const float*)d_in[29]};
    const float* n2b[2]  = {(const float*)d_in[17], (const float*)d_in[30]};
    const float* fc1w[2] = {(const float*)d_in[18], (const float*)d_in[31]};
    const float* fc1b[2] = {(const float*)d_in[19], (const float*)d_in[32]};
    const float* fc2w[2] = {(const float*)d_in[20], (const float*)d_in[33]};
    const float* fc2b[2] = {(const float*)d_in[21], (const float*)d_in[34]};

    float* out = (float*)d_out;
    float* ws = (float*)d_ws;
    const size_t n28 = (size_t)NB*RESX*RESX*DIMC;     // 19,267,584
    const size_t n14 = (size_t)NB*14*14*DIMC;         //  4,816,896
    const size_t n7  = (size_t)NB*7*7*DIMC;           //  1,204,224
    float* region0 = ws;                 // xln / conv scratch (n28)
    float* x7      = region0 + n28;      // global query source (n7)
    float* s0      = x7 + n7;
    float* s1      = s0 + NB*DIMC;
    float* scratch = s1 + NB*DIMC;       // x14 in phase A; qkv chunks in phase B
    size_t fixedf  = n28 + n7 + 2ull*NB*DIMC;
    if (ws_size < (fixedf + n14) * sizeof(float)) return;
    size_t scratchf = ws_size / sizeof(float) - fixedf;
    float* x14 = scratch;

    // ---- Phase A: GlobalQueryGen (from ORIGINAL x): 28 -> 14 -> 7
    for (int fe = 0; fe < 2; ++fe){
        int H = fe ? 14 : 28;
        int HW = H * H;
        const float* src = fe ? x14 : x;
        float* dst = fe ? x7 : x14;
        dw_gelu_kernel<<<NB*HW, DIMC, 0, stream>>>(src, fe_dw[fe], region0, H, H);
        se_reduce_kernel<<<NB, DIMC, 0, stream>>>(region0, s0, HW);
        se_mlp_kernel<<<NB, DIMC, 0, stream>>>(s0, fe_se1[fe], fe_se2[fe], s1);
        gemm192_kernel<<<NB*HW/16, 256, 0, stream>>>(region0, fe_pw[fe], nullptr,
                                                     src, s1, HW, region0);
        maxpool_kernel<<<NB*(H/2)*(H/2), DIMC, 0, stream>>>(region0, dst, H, H);
    }

    // images per qkv chunk (F<=576); proven ws size guarantees C >= 10
    int C = (int)(scratchf / (784ull * 576ull));
    if (C > NB) C = NB;
    if (C < 1) return;

    // ---- Phase B: two attention blocks (0=local, 1=global query)
    for (int blk = 0; blk < 2; ++blk){
        const float* xin = blk ? (const float*)out : x;
        ln_kernel<<<TOK28/4, 256, 0, stream>>>(xin, n1g[blk], n1b[blk], region0);
        int F    = blk ? 384 : 576;
        int qoff = blk ? -1  : 0;
        int koff = blk ? 0   : 192;
        int voff = blk ? 192 : 384;
        for (int b0 = 0; b0 < NB; b0 += C){
            int Ci = (NB - b0 < C) ? (NB - b0) : C;
            const float* inp = region0 + (size_t)b0*784*DIMC;
            gemmF_kernel<<<Ci*49, 256, 0, stream>>>(inp, qkvw[blk], qkvb[blk],
                                                    scratch, F);
            attn_core_kernel<<<Ci*16*NHEADS, 256, 0, stream>>>(
                region0, scratch, blk ? x7 : nullptr, rpb[blk],
                F, qoff, koff, voff, b0);
        }
        gemm192_kernel<<<TOK28/16, 256, 0, stream>>>(region0, prjw[blk], prjb[blk],
                                                     xin, nullptr, RESX*RESX, out);
        ln_kernel<<<TOK28/4, 256, 0, stream>>>(out, n2g[blk], n2b[blk], region0);
        mlp_kernel<<<TOK28/16, 256, 0, stream>>>(region0, fc1w[blk], fc1b[blk],
                                                 fc2w[blk], fc2b[blk], out);
    }
}

// Round 3
// 2709.024 us; speedup vs baseline: 5.1360x; 2.5456x over previous
//
#include <hip/hip_runtime.h>
#include <hip/hip_bf16.h>
#include <math.h>

#define NB     128
#define RESX   28
#define DIMC   192
#define NHEADS 6
#define WSZ    7
#define HD     32
#define NTOK   49
#define SCALE  0.17677669529663687f   // 32^-0.5
#define TOK28  (NB*RESX*RESX)         // 100352
#define HPAD   792                    // bf16 elems per h-row (16B-aligned, bank-spread)

typedef short  bf16x8 __attribute__((ext_vector_type(8)));
typedef float  f32x4  __attribute__((ext_vector_type(4)));

__device__ __forceinline__ float gelu_f(float x){
    return 0.5f * x * (1.0f + erff(x * 0.70710678118654752f));
}
__device__ __forceinline__ float dot4(float4 a, float4 b){
    return a.x*b.x + a.y*b.y + a.z*b.z + a.w*b.w;
}
__device__ __forceinline__ unsigned short f2bf(float f){
    unsigned int u = __float_as_uint(f);
    u += 0x7fffu + ((u >> 16) & 1u);          // RNE
    return (unsigned short)(u >> 16);
}
__device__ __forceinline__ bf16x8 pack8(float4 u, float4 v){
    bf16x8 r;
    r[0]=(short)f2bf(u.x); r[1]=(short)f2bf(u.y); r[2]=(short)f2bf(u.z); r[3]=(short)f2bf(u.w);
    r[4]=(short)f2bf(v.x); r[5]=(short)f2bf(v.y); r[6]=(short)f2bf(v.z); r[7]=(short)f2bf(v.w);
    return r;
}

// ---------------- LayerNorm: one wave per token (4 tokens / 256-thread block)
__global__ __launch_bounds__(256) void ln_kernel(const float* __restrict__ x,
        const float* __restrict__ g, const float* __restrict__ be,
        float* __restrict__ out)
{
    int wid = threadIdx.x >> 6, lane = threadIdx.x & 63;
    size_t tok = (size_t)blockIdx.x * 4 + wid;
    const float* xr = x + tok * DIMC;
    float v0 = xr[lane], v1 = xr[lane + 64], v2 = xr[lane + 128];
    float s  = v0 + v1 + v2;
    float sq = v0*v0 + v1*v1 + v2*v2;
    #pragma unroll
    for (int o = 32; o > 0; o >>= 1){ s += __shfl_xor(s, o); sq += __shfl_xor(sq, o); }
    float mean = s * (1.0f/DIMC);
    float var  = sq * (1.0f/DIMC) - mean*mean;
    float rstd = rsqrtf(var + 1e-5f);
    float* orow = out + tok * DIMC;
    orow[lane]     = (v0-mean)*rstd*g[lane]     + be[lane];
    orow[lane+64]  = (v1-mean)*rstd*g[lane+64]  + be[lane+64];
    orow[lane+128] = (v2-mean)*rstd*g[lane+128] + be[lane+128];
}

// ---------------- depthwise 3x3 (NHWC) + exact GELU
__global__ void dw_gelu_kernel(const float* __restrict__ x, const float* __restrict__ dw,
                               float* __restrict__ y, int H, int W)
{
    int p = blockIdx.x;
    int c = threadIdx.x;
    int w = p % W; int h = (p / W) % H; int b = p / (W*H);
    const float* base = x + (size_t)b*H*W*DIMC;
    float acc = 0.f;
    #pragma unroll
    for (int kh = 0; kh < 3; ++kh){
        int hh = h + kh - 1; if (hh < 0 || hh >= H) continue;
        #pragma unroll
        for (int kw = 0; kw < 3; ++kw){
            int ww = w + kw - 1; if (ww < 0 || ww >= W) continue;
            acc += base[((size_t)hh*W + ww)*DIMC + c] * dw[c*9 + kh*3 + kw];
        }
    }
    y[(size_t)p*DIMC + c] = gelu_f(acc);
}

// ---------------- SE: global average pool over HW
__global__ void se_reduce_kernel(const float* __restrict__ y, float* __restrict__ s0, int HW)
{
    int b = blockIdx.x; int c = threadIdx.x;
    const float* base = y + (size_t)b*HW*DIMC + c;
    float acc = 0.f;
    for (int p = 0; p < HW; ++p) acc += base[(size_t)p*DIMC];
    s0[b*DIMC + c] = acc / (float)HW;
}

// ---------------- SE: 192 -> gelu(48) -> sigmoid(192)
__global__ void se_mlp_kernel(const float* __restrict__ s0, const float* __restrict__ w1,
                              const float* __restrict__ w2, float* __restrict__ s)
{
    __shared__ float sl[DIMC];
    __shared__ float mid[48];
    int b = blockIdx.x; int t = threadIdx.x;
    sl[t] = s0[b*DIMC + t];
    __syncthreads();
    if (t < 48){
        float acc = 0.f;
        for (int c = 0; c < DIMC; ++c) acc += sl[c] * w1[t*DIMC + c];
        mid[t] = gelu_f(acc);
    }
    __syncthreads();
    float acc = 0.f;
    #pragma unroll 8
    for (int j = 0; j < 48; ++j) acc += mid[j] * w2[t*48 + j];
    s[b*DIMC + t] = 1.0f / (1.0f + expf(-acc));
}

// ---------------- f32 192x192 per-token GEMM (Phase A pointwise conv only)
__global__ __launch_bounds__(256) void gemm192_kernel(
    const float* __restrict__ in, const float* __restrict__ W,
    const float* __restrict__ bias, const float* __restrict__ res,
    const float* __restrict__ sv, int HW, float* __restrict__ out)
{
    __shared__ __align__(16) float xt[16*DIMC];
    int p0 = blockIdx.x * 16;
    int tid = threadIdx.x;
    if (sv){
        for (int i = tid; i < 16*DIMC; i += 256){
            int t = i / DIMC, c = i - t*DIMC;
            int p = p0 + t;
            xt[i] = in[(size_t)p*DIMC + c] * sv[(p/HW)*DIMC + c];
        }
    } else {
        for (int i = tid; i < 16*DIMC; i += 256)
            xt[i] = in[(size_t)p0*DIMC + i];
    }
    __syncthreads();
    for (int task = tid; task < 384; task += 256){
        int oct = task / 192, c = task - oct*192;
        const float4* wr4 = (const float4*)(W + (size_t)c*DIMC);
        float bb = bias ? bias[c] : 0.f;
        float acc[8];
        #pragma unroll
        for (int j = 0; j < 8; ++j) acc[j] = bb;
        const float* xb = xt + oct*8*DIMC;
        for (int k4 = 0; k4 < DIMC/4; ++k4){
            float4 w4 = wr4[k4];
            #pragma unroll
            for (int j = 0; j < 8; ++j){
                float4 a = ((const float4*)(xb + j*DIMC))[k4];
                acc[j] += dot4(a, w4);
            }
        }
        #pragma unroll
        for (int j = 0; j < 8; ++j){
            size_t o = (size_t)(p0 + oct*8 + j)*DIMC + c;
            out[o] = (res ? res[o] : 0.f) + acc[j];
        }
    }
}

// ---------------- maxpool 3x3 stride 2 pad 1 (NHWC)
__global__ void maxpool_kernel(const float* __restrict__ x, float* __restrict__ out,
                               int H, int W)
{
    int H2 = H >> 1, W2 = W >> 1;
    int p = blockIdx.x;
    int c = threadIdx.x;
    int w2 = p % W2; int h2 = (p / W2) % H2; int b = p / (W2*H2);
    float m = -INFINITY;
    #pragma unroll
    for (int dh = -1; dh <= 1; ++dh){
        int h = 2*h2 + dh; if (h < 0 || h >= H) continue;
        #pragma unroll
        for (int dw = -1; dw <= 1; ++dw){
            int w = 2*w2 + dw; if (w < 0 || w >= W) continue;
            m = fmaxf(m, x[(((size_t)b*H + h)*W + w)*DIMC + c]);
        }
    }
    out[(size_t)p*DIMC + c] = m;
}

// ---------------- weight pack: W[F][K] f32 -> fragment-ordered bf16
// frag (j = n-tile, s = k-step of 32): elem (lane,i) = W[j*16+(lane&15)][s*32+(lane>>4)*8+i]
__global__ __launch_bounds__(256) void pack_w_kernel(const float* __restrict__ W,
        unsigned short* __restrict__ out, int K)
{
    int t = blockIdx.x*256 + threadIdx.x;      // one thread = one (frag,lane) = 8 elems
    int lane = t & 63, frag = t >> 6;
    int ks = K >> 5;
    int j = frag / ks, s = frag - j*ks;
    const float* wr = W + (size_t)(j*16 + (lane & 15))*K + s*32 + ((lane>>4)<<3);
    float4 u = *(const float4*)wr;
    float4 v = *(const float4*)(wr + 4);
    bf16x8 r = pack8(u, v);
    *((bf16x8*)(out + (size_t)t*8)) = r;
}

// ---------------- MFMA GEMM (K=192): out[m][n] = bias[n] + sum_k in[m][k]W[n][k] (+res)
// swapped orientation: A=weight frags (n-rows), B=activation^T frags (token cols).
// 4 waves x 16 tokens = 64 tokens/block. N in {576,384,192}, even n-tile count.
__global__ __launch_bounds__(256) void gemm_mfma_kernel(
    const float* __restrict__ in, const unsigned short* __restrict__ Wp,
    const float* __restrict__ bias, const float* __restrict__ res,
    float* __restrict__ out, int N)
{
    int l = threadIdx.x & 63, w = threadIdx.x >> 6;
    int c = l & 15, g = l >> 4;
    size_t m0 = (size_t)blockIdx.x*64 + w*16;
    const float* arow = in + (m0 + c)*DIMC;
    bf16x8 bx[6];
    #pragma unroll
    for (int s = 0; s < 6; ++s){
        int k0 = s*32 + g*8;
        bx[s] = pack8(*(const float4*)(arow + k0), *(const float4*)(arow + k0 + 4));
    }
    int nt = N >> 4;
    for (int jp = 0; jp < (nt >> 1); ++jp){
        int j0 = 2*jp, j1 = 2*jp + 1;
        float4 b40 = *(const float4*)(bias + j0*16 + g*4);
        float4 b41 = *(const float4*)(bias + j1*16 + g*4);
        f32x4 acc0 = {b40.x, b40.y, b40.z, b40.w};
        f32x4 acc1 = {b41.x, b41.y, b41.z, b41.w};
        const bf16x8* wp0 = (const bf16x8*)(Wp + ((size_t)(j0*6)*64 + l)*8);
        const bf16x8* wp1 = (const bf16x8*)(Wp + ((size_t)(j1*6)*64 + l)*8);
        #pragma unroll
        for (int s = 0; s < 6; ++s){
            acc0 = __builtin_amdgcn_mfma_f32_16x16x32_bf16(wp0[s*64], bx[s], acc0, 0, 0, 0);
            acc1 = __builtin_amdgcn_mfma_f32_16x16x32_bf16(wp1[s*64], bx[s], acc1, 0, 0, 0);
        }
        size_t o0 = (m0 + c)*N + j0*16 + g*4;
        size_t o1 = (m0 + c)*N + j1*16 + g*4;
        float4 r0 = res ? *(const float4*)(res + o0) : make_float4(0.f,0.f,0.f,0.f);
        float4 r1 = res ? *(const float4*)(res + o1) : make_float4(0.f,0.f,0.f,0.f);
        *(float4*)(out + o0) = make_float4(acc0[0]+r0.x, acc0[1]+r0.y, acc0[2]+r0.z, acc0[3]+r0.w);
        *(float4*)(out + o1) = make_float4(acc1[0]+r1.x, acc1[1]+r1.y, acc1[2]+r1.z, acc1[3]+r1.w);
    }
}

// ---------------- fused MFMA MLP: xout += gelu(xln@W1^T+b1)@W2^T+b2 ; 64 tokens/block
__global__ __launch_bounds__(256) void mlp_mfma_kernel(
    const float* __restrict__ xln,
    const unsigned short* __restrict__ W1p, const float* __restrict__ b1,
    const unsigned short* __restrict__ W2p, const float* __restrict__ b2,
    float* __restrict__ xout)
{
    __shared__ unsigned short h[64*HPAD];      // 101376 B
    int l = threadIdx.x & 63, w = threadIdx.x >> 6;
    int c = l & 15, g = l >> 4;
    size_t m0 = (size_t)blockIdx.x*64 + w*16;
    const float* arow = xln + (m0 + c)*DIMC;
    bf16x8 bx[6];
    #pragma unroll
    for (int s = 0; s < 6; ++s){
        int k0 = s*32 + g*8;
        bx[s] = pack8(*(const float4*)(arow + k0), *(const float4*)(arow + k0 + 4));
    }
    unsigned short* hrow = h + (w*16 + c)*HPAD;
    // ---- fc1 + gelu -> h (bf16), wave-private rows
    for (int jp = 0; jp < 24; ++jp){
        int j0 = 2*jp, j1 = j0 + 1;
        float4 b40 = *(const float4*)(b1 + j0*16 + g*4);
        float4 b41 = *(const float4*)(b1 + j1*16 + g*4);
        f32x4 a0 = {b40.x, b40.y, b40.z, b40.w};
        f32x4 a1 = {b41.x, b41.y, b41.z, b41.w};
        const bf16x8* wp0 = (const bf16x8*)(W1p + ((size_t)(j0*6)*64 + l)*8);
        const bf16x8* wp1 = (const bf16x8*)(W1p + ((size_t)(j1*6)*64 + l)*8);
        #pragma unroll
        for (int s = 0; s < 6; ++s){
            a0 = __builtin_amdgcn_mfma_f32_16x16x32_bf16(wp0[s*64], bx[s], a0, 0, 0, 0);
            a1 = __builtin_amdgcn_mfma_f32_16x16x32_bf16(wp1[s*64], bx[s], a1, 0, 0, 0);
        }
        ushort4 h0, h1;
        h0.x = f2bf(gelu_f(a0[0])); h0.y = f2bf(gelu_f(a0[1]));
        h0.z = f2bf(gelu_f(a0[2])); h0.w = f2bf(gelu_f(a0[3]));
        h1.x = f2bf(gelu_f(a1[0])); h1.y = f2bf(gelu_f(a1[1]));
        h1.z = f2bf(gelu_f(a1[2])); h1.w = f2bf(gelu_f(a1[3]));
        *(ushort4*)(hrow + j0*16 + g*4) = h0;
        *(ushort4*)(hrow + j1*16 + g*4) = h1;
    }
    __syncthreads();
    // ---- fc2 (K=768) + residual
    f32x4 acc[12];
    #pragma unroll
    for (int j = 0; j < 12; ++j){
        float4 b4 = *(const float4*)(b2 + j*16 + g*4);
        acc[j][0]=b4.x; acc[j][1]=b4.y; acc[j][2]=b4.z; acc[j][3]=b4.w;
    }
    for (int ch = 0; ch < 4; ++ch){
        bf16x8 a2[6];
        #pragma unroll
        for (int s = 0; s < 6; ++s)
            a2[s] = *(const bf16x8*)(hrow + (ch*6 + s)*32 + g*8);
        #pragma unroll
        for (int j = 0; j < 12; ++j){
            const bf16x8* wp = (const bf16x8*)(W2p + ((size_t)(j*24 + ch*6)*64 + l)*8);
            #pragma unroll
            for (int s = 0; s < 6; ++s)
                acc[j] = __builtin_amdgcn_mfma_f32_16x16x32_bf16(wp[s*64], a2[s], acc[j], 0, 0, 0);
        }
    }
    #pragma unroll
    for (int j = 0; j < 12; ++j){
        size_t o = (m0 + c)*DIMC + j*16 + g*4;
        float4 r = *(const float4*)(xout + o);
        *(float4*)(xout + o) = make_float4(acc[j][0]+r.x, acc[j][1]+r.y,
                                           acc[j][2]+r.z, acc[j][3]+r.w);
    }
}

// ---------------- attention core: one block per (window, head)
__global__ __launch_bounds__(256) void attn_core_kernel(
    float* __restrict__ xio, const float* __restrict__ buf,
    const float* __restrict__ qg, const float* __restrict__ rpb,
    int F, int qoff, int koff, int voff, int b0)
{
    __shared__ float qs[NTOK*HD];
    __shared__ float kts[HD*NTOK];
    __shared__ float vs[NTOK*HD];
    __shared__ float sc[NTOK*NTOK];
    int blk = blockIdx.x;
    int hd  = blk % NHEADS;
    int wix = blk / NHEADS;
    int bloc = wix >> 4, win = wix & 15;
    int b = b0 + bloc;
    int wr = win >> 2, wc = win & 3;
    int tid = threadIdx.x;
    for (int i = tid; i < 3*NTOK*HD; i += 256){
        int which = i / (NTOK*HD), r = i - which*(NTOK*HD);
        int t = r >> 5, d = r & 31;
        int h = wr*WSZ + t/WSZ, w = wc*WSZ + t - (t/WSZ)*WSZ;
        size_t row = (size_t)bloc*784 + h*RESX + w;
        if (which == 0){
            float v = (qoff < 0)
                ? qg[((size_t)b*NTOK + t)*DIMC + hd*HD + d]
                : buf[row*F + qoff + hd*HD + d];
            qs[t*HD + d] = v * SCALE;
        } else if (which == 1){
            kts[d*NTOK + t] = buf[row*F + koff + hd*HD + d];
        } else {
            vs[t*HD + d] = buf[row*F + voff + hd*HD + d];
        }
    }
    __syncthreads();
    for (int i = tid; i < NTOK*NTOK; i += 256){
        int ti = i / NTOK, tj = i - (i/NTOK)*NTOK;
        float acc = 0.f;
        #pragma unroll 8
        for (int d = 0; d < HD; ++d) acc += qs[ti*HD + d] * kts[d*NTOK + tj];
        int ri = ti/WSZ, ci = ti - ri*WSZ;
        int rj = tj/WSZ, cj = tj - rj*WSZ;
        sc[i] = acc + rpb[((ri - rj + 6)*13 + (ci - cj + 6))*NHEADS + hd];
    }
    __syncthreads();
    if (tid < NTOK){
        float* row = sc + tid*NTOK;
        float m = -INFINITY;
        for (int j = 0; j < NTOK; ++j) m = fmaxf(m, row[j]);
        float ssum = 0.f;
        for (int j = 0; j < NTOK; ++j){ float e = __expf(row[j] - m); row[j] = e; ssum += e; }
        float inv = 1.0f / ssum;
        for (int j = 0; j < NTOK; ++j) row[j] *= inv;
    }
    __syncthreads();
    for (int i = tid; i < NTOK*HD; i += 256){
        int t = i >> 5, d = i & 31;
        const float* prow = sc + t*NTOK;
        float acc = 0.f;
        #pragma unroll 7
        for (int m2 = 0; m2 < NTOK; ++m2) acc += prow[m2] * vs[m2*HD + d];
        int h = wr*WSZ + t/WSZ, w = wc*WSZ + t - (t/WSZ)*WSZ;
        xio[(((size_t)b*RESX + h)*RESX + w)*DIMC + hd*HD + d] = acc;
    }
}

extern "C" void kernel_launch(void* const* d_in, const int* in_sizes, int n_in,
                              void* d_out, int out_size, void* d_ws, size_t ws_size,
                              hipStream_t stream)
{
    (void)in_sizes; (void)n_in; (void)out_size;
    const float* x = (const float*)d_in[0];
    const float* fe_dw[2]  = {(const float*)d_in[1], (const float*)d_in[5]};
    const float* fe_se1[2] = {(const float*)d_in[2], (const float*)d_in[6]};
    const float* fe_se2[2] = {(const float*)d_in[3], (const float*)d_in[7]};
    const float* fe_pw[2]  = {(const float*)d_in[4], (const float*)d_in[8]};
    const float* n1g[2]  = {(const float*)d_in[9],  (const float*)d_in[22]};
    const float* n1b[2]  = {(const float*)d_in[10], (const float*)d_in[23]};
    const float* qkvw[2] = {(const float*)d_in[11], (const float*)d_in[24]};
    const float* qkvb[2] = {(const float*)d_in[12], (const float*)d_in[25]};
    const float* rpb[2]  = {(const float*)d_in[13], (const float*)d_in[26]};
    const float* prjw[2] = {(const float*)d_in[14], (const float*)d_in[27]};
    const float* prjb[2] = {(const float*)d_in[15], (const float*)d_in[28]};
    const float* n2g[2]  = {(const float*)d_in[16], (const float*)d_in[29]};
    const float* n2b[2]  = {(const float*)d_in[17], (const float*)d_in[30]};
    const float* fc1w[2] = {(const float*)d_in[18], (const float*)d_in[31]};
    const float* fc1b[2] = {(const float*)d_in[19], (const float*)d_in[32]};
    const float* fc2w[2] = {(const float*)d_in[20], (const float*)d_in[33]};
    const float* fc2b[2] = {(const float*)d_in[21], (const float*)d_in[34]};

    float* out = (float*)d_out;
    float* ws = (float*)d_ws;
    const size_t n28 = (size_t)NB*RESX*RESX*DIMC;     // 19,267,584
    const size_t n14 = (size_t)NB*14*14*DIMC;         //  4,816,896
    const size_t n7  = (size_t)NB*7*7*DIMC;           //  1,204,224
    float* region0 = ws;
    float* x7      = region0 + n28;
    float* s0      = x7 + n7;
    float* s1      = s0 + NB*DIMC;
    float* dyn     = s1 + NB*DIMC;       // phase A: x14 ; phase B: packed weights + qkv
    size_t fixedf  = n28 + n7 + 2ull*NB*DIMC;
    if (ws_size < (fixedf + n14) * sizeof(float)) return;
    size_t dynf = ws_size / sizeof(float) - fixedf;
    float* x14 = dyn;

    // packed-weight layout inside dyn (ushort elems)
    unsigned short* pk = (unsigned short*)dyn;
    const size_t PK_QKV0 = 0;                 // 576x192
    const size_t PK_QKV1 = PK_QKV0 + 576*192; // 384x192
    const size_t PK_PRJ0 = PK_QKV1 + 384*192;
    const size_t PK_PRJ1 = PK_PRJ0 + 192*192;
    const size_t PK_FC10 = PK_PRJ1 + 192*192;
    const size_t PK_FC11 = PK_FC10 + 768*192;
    const size_t PK_FC20 = PK_FC11 + 768*192;
    const size_t PK_FC21 = PK_FC20 + 192*768;
    const size_t PK_TOT  = PK_FC21 + 192*768; // 847,872 ushorts
    float* qkvbuf = (float*)(pk + PK_TOT);
    size_t availf = dynf - PK_TOT/2;

    // ---- Phase A: GlobalQueryGen: 28 -> 14 -> 7 (f32; x14 lives in dyn)
    for (int fe = 0; fe < 2; ++fe){
        int H = fe ? 14 : 28;
        int HW = H * H;
        const float* src = fe ? x14 : x;
        float* dst = fe ? x7 : x14;
        dw_gelu_kernel<<<NB*HW, DIMC, 0, stream>>>(src, fe_dw[fe], region0, H, H);
        se_reduce_kernel<<<NB, DIMC, 0, stream>>>(region0, s0, HW);
        se_mlp_kernel<<<NB, DIMC, 0, stream>>>(s0, fe_se1[fe], fe_se2[fe], s1);
        gemm192_kernel<<<NB*HW/16, 256, 0, stream>>>(region0, fe_pw[fe], nullptr,
                                                     src, s1, HW, region0);
        maxpool_kernel<<<NB*(H/2)*(H/2), DIMC, 0, stream>>>(region0, dst, H, H);
    }

    // ---- pack weights to bf16 fragment order (overwrites x14 region; x14 dead now)
    pack_w_kernel<<<576*192/8/256, 256, 0, stream>>>(qkvw[0], pk + PK_QKV0, 192);
    pack_w_kernel<<<384*192/8/256, 256, 0, stream>>>(qkvw[1], pk + PK_QKV1, 192);
    pack_w_kernel<<<192*192/8/256, 256, 0, stream>>>(prjw[0], pk + PK_PRJ0, 192);
    pack_w_kernel<<<192*192/8/256, 256, 0, stream>>>(prjw[1], pk + PK_PRJ1, 192);
    pack_w_kernel<<<768*192/8/256, 256, 0, stream>>>(fc1w[0], pk + PK_FC10, 192);
    pack_w_kernel<<<768*192/8/256, 256, 0, stream>>>(fc1w[1], pk + PK_FC11, 192);
    pack_w_kernel<<<192*768/8/256, 256, 0, stream>>>(fc2w[0], pk + PK_FC20, 768);
    pack_w_kernel<<<192*768/8/256, 256, 0, stream>>>(fc2w[1], pk + PK_FC21, 768);

    // qkv chunking: multiples of 4 images (so tokens % 64 == 0)
    int C = (int)(availf / (784ull * 576ull));
    C &= ~3;
    if (C > NB) C = NB;
    if (C < 4) return;

    // ---- Phase B: two attention blocks (0=local, 1=global query)
    for (int blk = 0; blk < 2; ++blk){
        const float* xin = blk ? (const float*)out : x;
        ln_kernel<<<TOK28/4, 256, 0, stream>>>(xin, n1g[blk], n1b[blk], region0);
        int F    = blk ? 384 : 576;
        int qoff = blk ? -1  : 0;
        int koff = blk ? 0   : 192;
        int voff = blk ? 192 : 384;
        const unsigned short* qp = pk + (blk ? PK_QKV1 : PK_QKV0);
        for (int b0 = 0; b0 < NB; b0 += C){
            int Ci = (NB - b0 < C) ? (NB - b0) : C;
            const float* inp = region0 + (size_t)b0*784*DIMC;
            gemm_mfma_kernel<<<Ci*784/64, 256, 0, stream>>>(inp, qp, qkvb[blk],
                                                            nullptr, qkvbuf, F);
            attn_core_kernel<<<Ci*16*NHEADS, 256, 0, stream>>>(
                region0, qkvbuf, blk ? x7 : nullptr, rpb[blk],
                F, qoff, koff, voff, b0);
        }
        gemm_mfma_kernel<<<TOK28/64, 256, 0, stream>>>(region0,
            pk + (blk ? PK_PRJ1 : PK_PRJ0), prjb[blk], xin, out, DIMC);
        ln_kernel<<<TOK28/4, 256, 0, stream>>>(out, n2g[blk], n2b[blk], region0);
        mlp_mfma_kernel<<<TOK28/64, 256, 0, stream>>>(region0,
            pk + (blk ? PK_FC11 : PK_FC10), fc1b[blk],
            pk + (blk ? PK_FC21 : PK_FC20), fc2b[blk], out);
    }
}

// Round 4
// 2324.594 us; speedup vs baseline: 5.9854x; 1.1654x over previous
//
#include <hip/hip_runtime.h>
#include <hip/hip_bf16.h>
#include <math.h>

#define NB     128
#define RESX   28
#define DIMC   192
#define NHEADS 6
#define WSZ    7
#define HD     32
#define NTOK   49
#define SCALE  0.17677669529663687f   // 32^-0.5
#define TOK28  (NB*RESX*RESX)         // 100352

typedef short    bf16x8 __attribute__((ext_vector_type(8)));
typedef float    f32x4  __attribute__((ext_vector_type(4)));
typedef _Float16 f16x2  __attribute__((ext_vector_type(2)));

__device__ __forceinline__ float gelu_f(float x){
    return 0.5f * x * (1.0f + erff(x * 0.70710678118654752f));
}
__device__ __forceinline__ float dot4(float4 a, float4 b){
    return a.x*b.x + a.y*b.y + a.z*b.z + a.w*b.w;
}
__device__ __forceinline__ unsigned short f2bf(float f){
    unsigned int u = __float_as_uint(f);
    u += 0x7fffu + ((u >> 16) & 1u);          // RNE
    return (unsigned short)(u >> 16);
}
__device__ __forceinline__ float bf2f(unsigned short u){
    return __uint_as_float(((unsigned int)u) << 16);
}
__device__ __forceinline__ bf16x8 pack8(float4 u, float4 v){
    bf16x8 r;
    r[0]=(short)f2bf(u.x); r[1]=(short)f2bf(u.y); r[2]=(short)f2bf(u.z); r[3]=(short)f2bf(u.w);
    r[4]=(short)f2bf(v.x); r[5]=(short)f2bf(v.y); r[6]=(short)f2bf(v.z); r[7]=(short)f2bf(v.w);
    return r;
}
__device__ __forceinline__ float fdot2(f16x2 a, f16x2 b, float c){
#if __has_builtin(__builtin_amdgcn_fdot2)
    return __builtin_amdgcn_fdot2(a, b, c, false);
#else
    return c + (float)a[0]*(float)b[0] + (float)a[1]*(float)b[1];
#endif
}

// ---------------- LayerNorm: one wave per token (4 tokens / 256-thread block)
__global__ __launch_bounds__(256) void ln_kernel(const float* __restrict__ x,
        const float* __restrict__ g, const float* __restrict__ be,
        float* __restrict__ out)
{
    int wid = threadIdx.x >> 6, lane = threadIdx.x & 63;
    size_t tok = (size_t)blockIdx.x * 4 + wid;
    const float* xr = x + tok * DIMC;
    float v0 = xr[lane], v1 = xr[lane + 64], v2 = xr[lane + 128];
    float s  = v0 + v1 + v2;
    float sq = v0*v0 + v1*v1 + v2*v2;
    #pragma unroll
    for (int o = 32; o > 0; o >>= 1){ s += __shfl_xor(s, o); sq += __shfl_xor(sq, o); }
    float mean = s * (1.0f/DIMC);
    float var  = sq * (1.0f/DIMC) - mean*mean;
    float rstd = rsqrtf(var + 1e-5f);
    float* orow = out + tok * DIMC;
    orow[lane]     = (v0-mean)*rstd*g[lane]     + be[lane];
    orow[lane+64]  = (v1-mean)*rstd*g[lane+64]  + be[lane+64];
    orow[lane+128] = (v2-mean)*rstd*g[lane+128] + be[lane+128];
}

// ---------------- depthwise 3x3 (NHWC) + exact GELU
__global__ void dw_gelu_kernel(const float* __restrict__ x, const float* __restrict__ dw,
                               float* __restrict__ y, int H, int W)
{
    int p = blockIdx.x;
    int c = threadIdx.x;
    int w = p % W; int h = (p / W) % H; int b = p / (W*H);
    const float* base = x + (size_t)b*H*W*DIMC;
    float acc = 0.f;
    #pragma unroll
    for (int kh = 0; kh < 3; ++kh){
        int hh = h + kh - 1; if (hh < 0 || hh >= H) continue;
        #pragma unroll
        for (int kw = 0; kw < 3; ++kw){
            int ww = w + kw - 1; if (ww < 0 || ww >= W) continue;
            acc += base[((size_t)hh*W + ww)*DIMC + c] * dw[c*9 + kh*3 + kw];
        }
    }
    y[(size_t)p*DIMC + c] = gelu_f(acc);
}

// ---------------- SE: global average pool over HW
__global__ void se_reduce_kernel(const float* __restrict__ y, float* __restrict__ s0, int HW)
{
    int b = blockIdx.x; int c = threadIdx.x;
    const float* base = y + (size_t)b*HW*DIMC + c;
    float acc = 0.f;
    for (int p = 0; p < HW; ++p) acc += base[(size_t)p*DIMC];
    s0[b*DIMC + c] = acc / (float)HW;
}

// ---------------- SE: 192 -> gelu(48) -> sigmoid(192)
__global__ void se_mlp_kernel(const float* __restrict__ s0, const float* __restrict__ w1,
                              const float* __restrict__ w2, float* __restrict__ s)
{
    __shared__ float sl[DIMC];
    __shared__ float mid[48];
    int b = blockIdx.x; int t = threadIdx.x;
    sl[t] = s0[b*DIMC + t];
    __syncthreads();
    if (t < 48){
        float acc = 0.f;
        for (int c = 0; c < DIMC; ++c) acc += sl[c] * w1[t*DIMC + c];
        mid[t] = gelu_f(acc);
    }
    __syncthreads();
    float acc = 0.f;
    #pragma unroll 8
    for (int j = 0; j < 48; ++j) acc += mid[j] * w2[t*48 + j];
    s[b*DIMC + t] = 1.0f / (1.0f + expf(-acc));
}

// ---------------- f32 192x192 per-token GEMM (Phase A pointwise conv only)
__global__ __launch_bounds__(256) void gemm192_kernel(
    const float* __restrict__ in, const float* __restrict__ W,
    const float* __restrict__ bias, const float* __restrict__ res,
    const float* __restrict__ sv, int HW, float* __restrict__ out)
{
    __shared__ __align__(16) float xt[16*DIMC];
    int p0 = blockIdx.x * 16;
    int tid = threadIdx.x;
    if (sv){
        for (int i = tid; i < 16*DIMC; i += 256){
            int t = i / DIMC, c = i - t*DIMC;
            int p = p0 + t;
            xt[i] = in[(size_t)p*DIMC + c] * sv[(p/HW)*DIMC + c];
        }
    } else {
        for (int i = tid; i < 16*DIMC; i += 256)
            xt[i] = in[(size_t)p0*DIMC + i];
    }
    __syncthreads();
    for (int task = tid; task < 384; task += 256){
        int oct = task / 192, c = task - oct*192;
        const float4* wr4 = (const float4*)(W + (size_t)c*DIMC);
        float bb = bias ? bias[c] : 0.f;
        float acc[8];
        #pragma unroll
        for (int j = 0; j < 8; ++j) acc[j] = bb;
        const float* xb = xt + oct*8*DIMC;
        for (int k4 = 0; k4 < DIMC/4; ++k4){
            float4 w4 = wr4[k4];
            #pragma unroll
            for (int j = 0; j < 8; ++j){
                float4 a = ((const float4*)(xb + j*DIMC))[k4];
                acc[j] += dot4(a, w4);
            }
        }
        #pragma unroll
        for (int j = 0; j < 8; ++j){
            size_t o = (size_t)(p0 + oct*8 + j)*DIMC + c;
            out[o] = (res ? res[o] : 0.f) + acc[j];
        }
    }
}

// ---------------- maxpool 3x3 stride 2 pad 1 (NHWC)
__global__ void maxpool_kernel(const float* __restrict__ x, float* __restrict__ out,
                               int H, int W)
{
    int H2 = H >> 1, W2 = W >> 1;
    int p = blockIdx.x;
    int c = threadIdx.x;
    int w2 = p % W2; int h2 = (p / W2) % H2; int b = p / (W2*H2);
    float m = -INFINITY;
    #pragma unroll
    for (int dh = -1; dh <= 1; ++dh){
        int h = 2*h2 + dh; if (h < 0 || h >= H) continue;
        #pragma unroll
        for (int dw = -1; dw <= 1; ++dw){
            int w = 2*w2 + dw; if (w < 0 || w >= W) continue;
            m = fmaxf(m, x[(((size_t)b*H + h)*W + w)*DIMC + c]);
        }
    }
    out[(size_t)p*DIMC + c] = m;
}

// ---------------- weight pack: W[F][K] f32 -> fragment-ordered bf16
// frag (j = n-tile, s = k-step of 32): elem (lane,i) = W[j*16+(lane&15)][s*32+(lane>>4)*8+i]
__global__ __launch_bounds__(256) void pack_w_kernel(const float* __restrict__ W,
        unsigned short* __restrict__ out, int K)
{
    int t = blockIdx.x*256 + threadIdx.x;      // one thread = one (frag,lane) = 8 elems
    int lane = t & 63, frag = t >> 6;
    int ks = K >> 5;
    int j = frag / ks, s = frag - j*ks;
    const float* wr = W + (size_t)(j*16 + (lane & 15))*K + s*32 + ((lane>>4)<<3);
    float4 u = *(const float4*)wr;
    float4 v = *(const float4*)(wr + 4);
    bf16x8 r = pack8(u, v);
    *((bf16x8*)(out + (size_t)t*8)) = r;
}

// ---------------- MFMA GEMM (K=192): out[m][n] = bias[n] + sum_k in[m][k]W[n][k] (+res)
// swapped orientation: A=weight frags (n-rows), B=activation^T frags (token cols).
// 4 waves x 16 tokens = 64 tokens/block. N in {576,384,192}, even n-tile count.
// outb != nullptr -> bf16 output (no residual); else f32 (+res)
__global__ __launch_bounds__(256) void gemm_mfma_kernel(
    const float* __restrict__ in, const unsigned short* __restrict__ Wp,
    const float* __restrict__ bias, const float* __restrict__ res,
    float* __restrict__ out, unsigned short* __restrict__ outb, int N)
{
    int l = threadIdx.x & 63, w = threadIdx.x >> 6;
    int c = l & 15, g = l >> 4;
    size_t m0 = (size_t)blockIdx.x*64 + w*16;
    const float* arow = in + (m0 + c)*DIMC;
    bf16x8 bx[6];
    #pragma unroll
    for (int s = 0; s < 6; ++s){
        int k0 = s*32 + g*8;
        bx[s] = pack8(*(const float4*)(arow + k0), *(const float4*)(arow + k0 + 4));
    }
    int nt = N >> 4;
    for (int jp = 0; jp < (nt >> 1); ++jp){
        int j0 = 2*jp, j1 = 2*jp + 1;
        float4 b40 = *(const float4*)(bias + j0*16 + g*4);
        float4 b41 = *(const float4*)(bias + j1*16 + g*4);
        f32x4 acc0 = {b40.x, b40.y, b40.z, b40.w};
        f32x4 acc1 = {b41.x, b41.y, b41.z, b41.w};
        const bf16x8* wp0 = (const bf16x8*)(Wp + ((size_t)(j0*6)*64 + l)*8);
        const bf16x8* wp1 = (const bf16x8*)(Wp + ((size_t)(j1*6)*64 + l)*8);
        #pragma unroll
        for (int s = 0; s < 6; ++s){
            acc0 = __builtin_amdgcn_mfma_f32_16x16x32_bf16(wp0[s*64], bx[s], acc0, 0, 0, 0);
            acc1 = __builtin_amdgcn_mfma_f32_16x16x32_bf16(wp1[s*64], bx[s], acc1, 0, 0, 0);
        }
        size_t o0 = (m0 + c)*N + j0*16 + g*4;
        size_t o1 = (m0 + c)*N + j1*16 + g*4;
        if (outb){
            ushort4 u0, u1;
            u0.x=f2bf(acc0[0]); u0.y=f2bf(acc0[1]); u0.z=f2bf(acc0[2]); u0.w=f2bf(acc0[3]);
            u1.x=f2bf(acc1[0]); u1.y=f2bf(acc1[1]); u1.z=f2bf(acc1[2]); u1.w=f2bf(acc1[3]);
            *(ushort4*)(outb + o0) = u0;
            *(ushort4*)(outb + o1) = u1;
        } else {
            float4 r0 = res ? *(const float4*)(res + o0) : make_float4(0.f,0.f,0.f,0.f);
            float4 r1 = res ? *(const float4*)(res + o1) : make_float4(0.f,0.f,0.f,0.f);
            *(float4*)(out + o0) = make_float4(acc0[0]+r0.x, acc0[1]+r0.y, acc0[2]+r0.z, acc0[3]+r0.w);
            *(float4*)(out + o1) = make_float4(acc1[0]+r1.x, acc1[1]+r1.y, acc1[2]+r1.z, acc1[3]+r1.w);
        }
    }
}

// ---------------- fused MFMA MLP, chunked hidden (wave-private LDS, no barriers)
// xout += gelu(xln@W1^T+b1)@W2^T+b2 ; 64 tokens/block, h in 4 chunks of 192
__global__ __launch_bounds__(256, 3) void mlp_mfma_kernel(
    const float* __restrict__ xln,
    const unsigned short* __restrict__ W1p, const float* __restrict__ b1,
    const unsigned short* __restrict__ W2p, const float* __restrict__ b2,
    float* __restrict__ xout)
{
    __shared__ __align__(16) unsigned short h[4][16][200];   // 25600 B, wave-private rows
    int l = threadIdx.x & 63, w = threadIdx.x >> 6;
    int c = l & 15, g = l >> 4;
    size_t m0 = (size_t)blockIdx.x*64 + w*16;
    const float* arow = xln + (m0 + c)*DIMC;
    bf16x8 bx[6];
    #pragma unroll
    for (int s = 0; s < 6; ++s){
        int k0 = s*32 + g*8;
        bx[s] = pack8(*(const float4*)(arow + k0), *(const float4*)(arow + k0 + 4));
    }
    unsigned short* hrow = &h[w][c][0];
    f32x4 acc[12];
    #pragma unroll
    for (int j = 0; j < 12; ++j){
        float4 b4 = *(const float4*)(b2 + j*16 + g*4);
        acc[j][0]=b4.x; acc[j][1]=b4.y; acc[j][2]=b4.z; acc[j][3]=b4.w;
    }
    for (int ch = 0; ch < 4; ++ch){
        // ---- fc1 + gelu for hidden features [ch*192, ch*192+192)
        #pragma unroll
        for (int jp = 0; jp < 6; ++jp){
            int j0 = ch*12 + 2*jp, j1 = j0 + 1;
            float4 b40 = *(const float4*)(b1 + j0*16 + g*4);
            float4 b41 = *(const float4*)(b1 + j1*16 + g*4);
            f32x4 a0 = {b40.x, b40.y, b40.z, b40.w};
            f32x4 a1 = {b41.x, b41.y, b41.z, b41.w};
            const bf16x8* wp0 = (const bf16x8*)(W1p + ((size_t)(j0*6)*64 + l)*8);
            const bf16x8* wp1 = (const bf16x8*)(W1p + ((size_t)(j1*6)*64 + l)*8);
            #pragma unroll
            for (int s = 0; s < 6; ++s){
                a0 = __builtin_amdgcn_mfma_f32_16x16x32_bf16(wp0[s*64], bx[s], a0, 0, 0, 0);
                a1 = __builtin_amdgcn_mfma_f32_16x16x32_bf16(wp1[s*64], bx[s], a1, 0, 0, 0);
            }
            ushort4 h0, h1;
            h0.x = f2bf(gelu_f(a0[0])); h0.y = f2bf(gelu_f(a0[1]));
            h0.z = f2bf(gelu_f(a0[2])); h0.w = f2bf(gelu_f(a0[3]));
            h1.x = f2bf(gelu_f(a1[0])); h1.y = f2bf(gelu_f(a1[1]));
            h1.z = f2bf(gelu_f(a1[2])); h1.w = f2bf(gelu_f(a1[3]));
            *(ushort4*)(hrow + (2*jp)*16   + g*4) = h0;
            *(ushort4*)(hrow + (2*jp+1)*16 + g*4) = h1;
        }
        // ---- fc2 partial over this k-chunk (wave-private: no barrier needed)
        bf16x8 a2[6];
        #pragma unroll
        for (int s = 0; s < 6; ++s)
            a2[s] = *(const bf16x8*)(hrow + s*32 + g*8);
        #pragma unroll
        for (int j = 0; j < 12; ++j){
            const bf16x8* wp = (const bf16x8*)(W2p + ((size_t)(j*24 + ch*6)*64 + l)*8);
            #pragma unroll
            for (int s = 0; s < 6; ++s)
                acc[j] = __builtin_amdgcn_mfma_f32_16x16x32_bf16(wp[s*64], a2[s], acc[j], 0, 0, 0);
        }
    }
    #pragma unroll
    for (int j = 0; j < 12; ++j){
        size_t o = (m0 + c)*DIMC + j*16 + g*4;
        float4 r = *(const float4*)(xout + o);
        *(float4*)(xout + o) = make_float4(acc[j][0]+r.x, acc[j][1]+r.y,
                                           acc[j][2]+r.z, acc[j][3]+r.w);
    }
}

// ---------------- attention core v2: one block per (window, head), fp16-dot2
// bufb: bf16 qkv rows [Ci*784, F]; O written f32 over xio at pixel/head-slice.
__global__ __launch_bounds__(256) void attn_core_kernel(
    float* __restrict__ xio, const unsigned short* __restrict__ bufb,
    const float* __restrict__ qg, const float* __restrict__ rpb,
    int F, int qoff, int koff, int voff, int b0)
{
    __shared__ f16x2 qh[NTOK][17];             // [.][16] used, odd stride
    __shared__ f16x2 kh[NTOK][17];
    __shared__ float sc[NTOK*NTOK];
    __shared__ f16x2 ph[NTOK][27];             // [.][25] used
    __shared__ f16x2 vt[HD][27];               // v^T, m-pairs
    __shared__ unsigned short vlin[NTOK][34];  // raw bf16 v rows
    __shared__ float sinv[NTOK];
    int blk = blockIdx.x;
    int hd  = blk % NHEADS;
    int wix = blk / NHEADS;
    int bloc = wix >> 4, win = wix & 15;
    int b = b0 + bloc;
    int wr = win >> 2, wc = win & 3;
    int tid = threadIdx.x;
    // ---- load q (scaled), k, v(raw) : 3*784 items of 2 elems
    for (int i = tid; i < 3*784; i += 256){
        int which = i / 784, r = i - which*784;
        int t = r >> 4, d2 = r & 15;
        int h = wr*WSZ + t/WSZ, w = wc*WSZ + t - (t/WSZ)*WSZ;
        size_t row = (size_t)bloc*784 + h*RESX + w;
        if (which == 0){
            float f0, f1;
            if (qoff < 0){
                const float* qp = qg + ((size_t)b*NTOK + t)*DIMC + hd*HD + 2*d2;
                f0 = qp[0]; f1 = qp[1];
            } else {
                ushort2 u = *(const ushort2*)(bufb + row*F + qoff + hd*HD + 2*d2);
                f0 = bf2f(u.x); f1 = bf2f(u.y);
            }
            f16x2 qv; qv[0] = (_Float16)(f0*SCALE); qv[1] = (_Float16)(f1*SCALE);
            qh[t][d2] = qv;
        } else if (which == 1){
            ushort2 u = *(const ushort2*)(bufb + row*F + koff + hd*HD + 2*d2);
            f16x2 kv; kv[0] = (_Float16)bf2f(u.x); kv[1] = (_Float16)bf2f(u.y);
            kh[t][d2] = kv;
        } else {
            ushort2 u = *(const ushort2*)(bufb + row*F + voff + hd*HD + 2*d2);
            *(ushort2*)(&vlin[t][2*d2]) = u;
        }
    }
    __syncthreads();
    // ---- scores (+rel bias) and v^T build
    for (int i = tid; i < 2401 + 800; i += 256){
        if (i < 2401){
            int ti = i / NTOK, tj = i - (i/NTOK)*NTOK;
            int ri = ti/WSZ, ci = ti - ri*WSZ;
            int rj = tj/WSZ, cj = tj - rj*WSZ;
            float acc = rpb[((ri - rj + 6)*13 + (ci - cj + 6))*NHEADS + hd];
            #pragma unroll
            for (int dd = 0; dd < 16; ++dd)
                acc = fdot2(qh[ti][dd], kh[tj][dd], acc);
            sc[i] = acc;
        } else {
            int j = i - 2401;
            int d = j / 25, mm = j - (j/25)*25;
            float v0 = bf2f(vlin[2*mm][d]);
            float v1 = (2*mm + 1 < NTOK) ? bf2f(vlin[2*mm+1][d]) : 0.f;
            f16x2 vv; vv[0] = (_Float16)v0; vv[1] = (_Float16)v1;
            vt[d][mm] = vv;
        }
    }
    __syncthreads();
    // ---- P = exp(sc) packed to half2 pairs (no max-sub: scores are tiny)
    for (int i = tid; i < 49*25; i += 256){
        int row = i / 25, mm = i - (i/25)*25;
        float e0 = __expf(sc[row*NTOK + 2*mm]);
        float e1 = (2*mm + 1 < NTOK) ? __expf(sc[row*NTOK + 2*mm + 1]) : 0.f;
        f16x2 pv; pv[0] = (_Float16)e0; pv[1] = (_Float16)e1;
        ph[row][mm] = pv;
    }
    __syncthreads();
    // ---- row sums (4 lanes per row)
    if (tid < 196){
        int row = tid >> 2, q0 = tid & 3;
        float s = 0.f;
        for (int mm = q0; mm < 25; mm += 4)
            s += (float)ph[row][mm][0] + (float)ph[row][mm][1];
        s += __shfl_xor(s, 1);
        s += __shfl_xor(s, 2);
        if (q0 == 0) sinv[row] = 1.0f / s;
    }
    __syncthreads();
    // ---- o = (P @ v) * sinv, write back (win_rev via pixel indexing)
    for (int i = tid; i < NTOK*HD; i += 256){
        int t = i >> 5, d = i & 31;
        float acc = 0.f;
        #pragma unroll
        for (int mm = 0; mm < 25; ++mm)
            acc = fdot2(ph[t][mm], vt[d][mm], acc);
        int h = wr*WSZ + t/WSZ, w = wc*WSZ + t - (t/WSZ)*WSZ;
        xio[(((size_t)b*RESX + h)*RESX + w)*DIMC + hd*HD + d] = acc * sinv[t];
    }
}

extern "C" void kernel_launch(void* const* d_in, const int* in_sizes, int n_in,
                              void* d_out, int out_size, void* d_ws, size_t ws_size,
                              hipStream_t stream)
{
    (void)in_sizes; (void)n_in; (void)out_size;
    const float* x = (const float*)d_in[0];
    const float* fe_dw[2]  = {(const float*)d_in[1], (const float*)d_in[5]};
    const float* fe_se1[2] = {(const float*)d_in[2], (const float*)d_in[6]};
    const float* fe_se2[2] = {(const float*)d_in[3], (const float*)d_in[7]};
    const float* fe_pw[2]  = {(const float*)d_in[4], (const float*)d_in[8]};
    const float* n1g[2]  = {(const float*)d_in[9],  (const float*)d_in[22]};
    const float* n1b[2]  = {(const float*)d_in[10], (const float*)d_in[23]};
    const float* qkvw[2] = {(const float*)d_in[11], (const float*)d_in[24]};
    const float* qkvb[2] = {(const float*)d_in[12], (const float*)d_in[25]};
    const float* rpb[2]  = {(const float*)d_in[13], (const float*)d_in[26]};
    const float* prjw[2] = {(const float*)d_in[14], (const float*)d_in[27]};
    const float* prjb[2] = {(const float*)d_in[15], (const float*)d_in[28]};
    const float* n2g[2]  = {(const float*)d_in[16], (const float*)d_in[29]};
    const float* n2b[2]  = {(const float*)d_in[17], (const float*)d_in[30]};
    const float* fc1w[2] = {(const float*)d_in[18], (const float*)d_in[31]};
    const float* fc1b[2] = {(const float*)d_in[19], (const float*)d_in[32]};
    const float* fc2w[2] = {(const float*)d_in[20], (const float*)d_in[33]};
    const float* fc2b[2] = {(const float*)d_in[21], (const float*)d_in[34]};

    float* out = (float*)d_out;
    float* ws = (float*)d_ws;
    const size_t n28 = (size_t)NB*RESX*RESX*DIMC;     // 19,267,584
    const size_t n14 = (size_t)NB*14*14*DIMC;         //  4,816,896
    const size_t n7  = (size_t)NB*7*7*DIMC;           //  1,204,224
    float* region0 = ws;
    float* x7      = region0 + n28;
    float* s0      = x7 + n7;
    float* s1      = s0 + NB*DIMC;
    float* dyn     = s1 + NB*DIMC;       // phase A: x14 ; phase B: packed weights + qkv
    size_t fixedf  = n28 + n7 + 2ull*NB*DIMC;
    if (ws_size < (fixedf + n14) * sizeof(float)) return;
    size_t dynf = ws_size / sizeof(float) - fixedf;
    float* x14 = dyn;

    // packed-weight layout inside dyn (ushort elems)
    unsigned short* pk = (unsigned short*)dyn;
    const size_t PK_QKV0 = 0;                 // 576x192
    const size_t PK_QKV1 = PK_QKV0 + 576*192; // 384x192
    const size_t PK_PRJ0 = PK_QKV1 + 384*192;
    const size_t PK_PRJ1 = PK_PRJ0 + 192*192;
    const size_t PK_FC10 = PK_PRJ1 + 192*192;
    const size_t PK_FC11 = PK_FC10 + 768*192;
    const size_t PK_FC20 = PK_FC11 + 768*192;
    const size_t PK_FC21 = PK_FC20 + 192*768;
    const size_t PK_TOT  = PK_FC21 + 192*768; // 847,872 ushorts
    unsigned short* qkvbuf = pk + PK_TOT;
    size_t availu = 2*dynf - PK_TOT;          // ushort capacity for qkv buffer

    // ---- Phase A: GlobalQueryGen: 28 -> 14 -> 7 (f32; x14 lives in dyn)
    for (int fe = 0; fe < 2; ++fe){
        int H = fe ? 14 : 28;
        int HW = H * H;
        const float* src = fe ? x14 : x;
        float* dst = fe ? x7 : x14;
        dw_gelu_kernel<<<NB*HW, DIMC, 0, stream>>>(src, fe_dw[fe], region0, H, H);
        se_reduce_kernel<<<NB, DIMC, 0, stream>>>(region0, s0, HW);
        se_mlp_kernel<<<NB, DIMC, 0, stream>>>(s0, fe_se1[fe], fe_se2[fe], s1);
        gemm192_kernel<<<NB*HW/16, 256, 0, stream>>>(region0, fe_pw[fe], nullptr,
                                                     src, s1, HW, region0);
        maxpool_kernel<<<NB*(H/2)*(H/2), DIMC, 0, stream>>>(region0, dst, H, H);
    }

    // ---- pack weights to bf16 fragment order (overwrites x14 region; x14 dead now)
    pack_w_kernel<<<576*192/8/256, 256, 0, stream>>>(qkvw[0], pk + PK_QKV0, 192);
    pack_w_kernel<<<384*192/8/256, 256, 0, stream>>>(qkvw[1], pk + PK_QKV1, 192);
    pack_w_kernel<<<192*192/8/256, 256, 0, stream>>>(prjw[0], pk + PK_PRJ0, 192);
    pack_w_kernel<<<192*192/8/256, 256, 0, stream>>>(prjw[1], pk + PK_PRJ1, 192);
    pack_w_kernel<<<768*192/8/256, 256, 0, stream>>>(fc1w[0], pk + PK_FC10, 192);
    pack_w_kernel<<<768*192/8/256, 256, 0, stream>>>(fc1w[1], pk + PK_FC11, 192);
    pack_w_kernel<<<192*768/8/256, 256, 0, stream>>>(fc2w[0], pk + PK_FC20, 768);
    pack_w_kernel<<<192*768/8/256, 256, 0, stream>>>(fc2w[1], pk + PK_FC21, 768);

    // qkv chunking: multiples of 4 images (so tokens % 64 == 0)
    int C = (int)(availu / (784ull * 576ull));
    C &= ~3;
    if (C > NB) C = NB;
    if (C < 4) return;

    // ---- Phase B: two attention blocks (0=local, 1=global query)
    for (int blk = 0; blk < 2; ++blk){
        const float* xin = blk ? (const float*)out : x;
        ln_kernel<<<TOK28/4, 256, 0, stream>>>(xin, n1g[blk], n1b[blk], region0);
        int F    = blk ? 384 : 576;
        int qoff = blk ? -1  : 0;
        int koff = blk ? 0   : 192;
        int voff = blk ? 192 : 384;
        const unsigned short* qp = pk + (blk ? PK_QKV1 : PK_QKV0);
        for (int b0 = 0; b0 < NB; b0 += C){
            int Ci = (NB - b0 < C) ? (NB - b0) : C;
            const float* inp = region0 + (size_t)b0*784*DIMC;
            gemm_mfma_kernel<<<Ci*784/64, 256, 0, stream>>>(inp, qp, qkvb[blk],
                                                            nullptr, nullptr, qkvbuf, F);
            attn_core_kernel<<<Ci*16*NHEADS, 256, 0, stream>>>(
                region0, qkvbuf, blk ? x7 : nullptr, rpb[blk],
                F, qoff, koff, voff, b0);
        }
        gemm_mfma_kernel<<<TOK28/64, 256, 0, stream>>>(region0,
            pk + (blk ? PK_PRJ1 : PK_PRJ0), prjb[blk], xin, out, nullptr, DIMC);
        ln_kernel<<<TOK28/4, 256, 0, stream>>>(out, n2g[blk], n2b[blk], region0);
        mlp_mfma_kernel<<<TOK28/64, 256, 0, stream>>>(region0,
            pk + (blk ? PK_FC11 : PK_FC10), fc1b[blk],
            pk + (blk ? PK_FC21 : PK_FC20), fc2b[blk], out);
    }
}

// Round 5
// 2198.352 us; speedup vs baseline: 6.3291x; 1.0574x over previous
//
#include <hip/hip_runtime.h>
#include <hip/hip_bf16.h>
#include <math.h>

#define NB     128
#define RESX   28
#define DIMC   192
#define NHEADS 6
#define WSZ    7
#define HD     32
#define NTOK   49
#define SCALE  0.17677669529663687f   // 32^-0.5
#define TOK28  (NB*RESX*RESX)         // 100352

typedef short    bf16x8 __attribute__((ext_vector_type(8)));
typedef float    f32x4  __attribute__((ext_vector_type(4)));
typedef _Float16 f16x2  __attribute__((ext_vector_type(2)));

__device__ __forceinline__ float gelu_f(float x){
    return 0.5f * x * (1.0f + erff(x * 0.70710678118654752f));
}
__device__ __forceinline__ float dot4(float4 a, float4 b){
    return a.x*b.x + a.y*b.y + a.z*b.z + a.w*b.w;
}
__device__ __forceinline__ unsigned short f2bf(float f){
    unsigned int u = __float_as_uint(f);
    u += 0x7fffu + ((u >> 16) & 1u);          // RNE
    return (unsigned short)(u >> 16);
}
__device__ __forceinline__ float bf2f(unsigned short u){
    return __uint_as_float(((unsigned int)u) << 16);
}
__device__ __forceinline__ bf16x8 pack8(float4 u, float4 v){
    bf16x8 r;
    r[0]=(short)f2bf(u.x); r[1]=(short)f2bf(u.y); r[2]=(short)f2bf(u.z); r[3]=(short)f2bf(u.w);
    r[4]=(short)f2bf(v.x); r[5]=(short)f2bf(v.y); r[6]=(short)f2bf(v.z); r[7]=(short)f2bf(v.w);
    return r;
}
__device__ __forceinline__ float fdot2(f16x2 a, f16x2 b, float c){
#if __has_builtin(__builtin_amdgcn_fdot2)
    return __builtin_amdgcn_fdot2(a, b, c, false);
#else
    return c + (float)a[0]*(float)b[0] + (float)a[1]*(float)b[1];
#endif
}

// ---------------- LayerNorm: one wave per token (4 tokens / 256-thread block)
__global__ __launch_bounds__(256) void ln_kernel(const float* __restrict__ x,
        const float* __restrict__ g, const float* __restrict__ be,
        float* __restrict__ out)
{
    int wid = threadIdx.x >> 6, lane = threadIdx.x & 63;
    size_t tok = (size_t)blockIdx.x * 4 + wid;
    const float* xr = x + tok * DIMC;
    float v0 = xr[lane], v1 = xr[lane + 64], v2 = xr[lane + 128];
    float s  = v0 + v1 + v2;
    float sq = v0*v0 + v1*v1 + v2*v2;
    #pragma unroll
    for (int o = 32; o > 0; o >>= 1){ s += __shfl_xor(s, o); sq += __shfl_xor(sq, o); }
    float mean = s * (1.0f/DIMC);
    float var  = sq * (1.0f/DIMC) - mean*mean;
    float rstd = rsqrtf(var + 1e-5f);
    float* orow = out + tok * DIMC;
    orow[lane]     = (v0-mean)*rstd*g[lane]     + be[lane];
    orow[lane+64]  = (v1-mean)*rstd*g[lane+64]  + be[lane+64];
    orow[lane+128] = (v2-mean)*rstd*g[lane+128] + be[lane+128];
}

// ---------------- depthwise 3x3 (NHWC) + exact GELU
__global__ void dw_gelu_kernel(const float* __restrict__ x, const float* __restrict__ dw,
                               float* __restrict__ y, int H, int W)
{
    int p = blockIdx.x;
    int c = threadIdx.x;
    int w = p % W; int h = (p / W) % H; int b = p / (W*H);
    const float* base = x + (size_t)b*H*W*DIMC;
    float acc = 0.f;
    #pragma unroll
    for (int kh = 0; kh < 3; ++kh){
        int hh = h + kh - 1; if (hh < 0 || hh >= H) continue;
        #pragma unroll
        for (int kw = 0; kw < 3; ++kw){
            int ww = w + kw - 1; if (ww < 0 || ww >= W) continue;
            acc += base[((size_t)hh*W + ww)*DIMC + c] * dw[c*9 + kh*3 + kw];
        }
    }
    y[(size_t)p*DIMC + c] = gelu_f(acc);
}

// ---------------- SE: global average pool over HW
__global__ void se_reduce_kernel(const float* __restrict__ y, float* __restrict__ s0, int HW)
{
    int b = blockIdx.x; int c = threadIdx.x;
    const float* base = y + (size_t)b*HW*DIMC + c;
    float acc = 0.f;
    for (int p = 0; p < HW; ++p) acc += base[(size_t)p*DIMC];
    s0[b*DIMC + c] = acc / (float)HW;
}

// ---------------- SE: 192 -> gelu(48) -> sigmoid(192)
__global__ void se_mlp_kernel(const float* __restrict__ s0, const float* __restrict__ w1,
                              const float* __restrict__ w2, float* __restrict__ s)
{
    __shared__ float sl[DIMC];
    __shared__ float mid[48];
    int b = blockIdx.x; int t = threadIdx.x;
    sl[t] = s0[b*DIMC + t];
    __syncthreads();
    if (t < 48){
        float acc = 0.f;
        for (int c = 0; c < DIMC; ++c) acc += sl[c] * w1[t*DIMC + c];
        mid[t] = gelu_f(acc);
    }
    __syncthreads();
    float acc = 0.f;
    #pragma unroll 8
    for (int j = 0; j < 48; ++j) acc += mid[j] * w2[t*48 + j];
    s[b*DIMC + t] = 1.0f / (1.0f + expf(-acc));
}

// ---------------- f32 192x192 per-token GEMM (Phase A pointwise conv only)
__global__ __launch_bounds__(256) void gemm192_kernel(
    const float* __restrict__ in, const float* __restrict__ W,
    const float* __restrict__ bias, const float* __restrict__ res,
    const float* __restrict__ sv, int HW, float* __restrict__ out)
{
    __shared__ __align__(16) float xt[16*DIMC];
    int p0 = blockIdx.x * 16;
    int tid = threadIdx.x;
    if (sv){
        for (int i = tid; i < 16*DIMC; i += 256){
            int t = i / DIMC, c = i - t*DIMC;
            int p = p0 + t;
            xt[i] = in[(size_t)p*DIMC + c] * sv[(p/HW)*DIMC + c];
        }
    } else {
        for (int i = tid; i < 16*DIMC; i += 256)
            xt[i] = in[(size_t)p0*DIMC + i];
    }
    __syncthreads();
    for (int task = tid; task < 384; task += 256){
        int oct = task / 192, c = task - oct*192;
        const float4* wr4 = (const float4*)(W + (size_t)c*DIMC);
        float bb = bias ? bias[c] : 0.f;
        float acc[8];
        #pragma unroll
        for (int j = 0; j < 8; ++j) acc[j] = bb;
        const float* xb = xt + oct*8*DIMC;
        for (int k4 = 0; k4 < DIMC/4; ++k4){
            float4 w4 = wr4[k4];
            #pragma unroll
            for (int j = 0; j < 8; ++j){
                float4 a = ((const float4*)(xb + j*DIMC))[k4];
                acc[j] += dot4(a, w4);
            }
        }
        #pragma unroll
        for (int j = 0; j < 8; ++j){
            size_t o = (size_t)(p0 + oct*8 + j)*DIMC + c;
            out[o] = (res ? res[o] : 0.f) + acc[j];
        }
    }
}

// ---------------- maxpool 3x3 stride 2 pad 1 (NHWC)
__global__ void maxpool_kernel(const float* __restrict__ x, float* __restrict__ out,
                               int H, int W)
{
    int H2 = H >> 1, W2 = W >> 1;
    int p = blockIdx.x;
    int c = threadIdx.x;
    int w2 = p % W2; int h2 = (p / W2) % H2; int b = p / (W2*H2);
    float m = -INFINITY;
    #pragma unroll
    for (int dh = -1; dh <= 1; ++dh){
        int h = 2*h2 + dh; if (h < 0 || h >= H) continue;
        #pragma unroll
        for (int dw = -1; dw <= 1; ++dw){
            int w = 2*w2 + dw; if (w < 0 || w >= W) continue;
            m = fmaxf(m, x[(((size_t)b*H + h)*W + w)*DIMC + c]);
        }
    }
    out[(size_t)p*DIMC + c] = m;
}

// ---------------- weight pack: W[F][K] f32 -> fragment-ordered bf16
// frag (j = n-tile, s = k-step of 32): elem (lane,i) = W[j*16+(lane&15)][s*32+(lane>>4)*8+i]
__global__ __launch_bounds__(256) void pack_w_kernel(const float* __restrict__ W,
        unsigned short* __restrict__ out, int K)
{
    int t = blockIdx.x*256 + threadIdx.x;      // one thread = one (frag,lane) = 8 elems
    int lane = t & 63, frag = t >> 6;
    int ks = K >> 5;
    int j = frag / ks, s = frag - j*ks;
    const float* wr = W + (size_t)(j*16 + (lane & 15))*K + s*32 + ((lane>>4)<<3);
    float4 u = *(const float4*)wr;
    float4 v = *(const float4*)(wr + 4);
    bf16x8 r = pack8(u, v);
    *((bf16x8*)(out + (size_t)t*8)) = r;
}

// ---------------- weight-stationary MFMA GEMM (K=192), n-chunk of 192 staged in LDS
// out[m][n] = bias[n] + sum_k in[m][k]W[n][k] (+res).  grid = (grid_m, N/192).
// Each wave: 2*ppw token-tiles as pairs; weight frag from LDS feeds 2 MFMAs.
// outb!=null -> bf16 out (no residual); else f32 out (+res).
__global__ __launch_bounds__(256) void gemmW_kernel(
    const float* __restrict__ in, const unsigned short* __restrict__ Wp,
    const float* __restrict__ bias, const float* __restrict__ res,
    float* __restrict__ out, unsigned short* __restrict__ outb,
    int N, int M, int ppw)
{
    __shared__ __align__(16) unsigned short wlds[72*512];  // 72 frags = 73728 B
    __shared__ __align__(16) float sbias[192];
    int tid = threadIdx.x;
    int l = tid & 63, w = tid >> 6, c = l & 15, g = l >> 4;
    int nc = blockIdx.y;
    const bf16x8* wsrc = (const bf16x8*)(Wp + (size_t)nc*36864);
    bf16x8* wdst = (bf16x8*)wlds;
    #pragma unroll 2
    for (int i = tid; i < 4608; i += 256) wdst[i] = wsrc[i];
    if (tid < 48) ((float4*)sbias)[tid] = ((const float4*)(bias + nc*192))[tid];
    __syncthreads();
    size_t mbase = (size_t)blockIdx.x*(128*ppw) + (size_t)w*(32*ppw);
    for (int p = 0; p < ppw; ++p){
        size_t m0 = mbase + (size_t)p*32;
        if ((long)m0 >= M) break;
        bool st1 = (long)(m0 + 16) < M;
        const float* ar0 = in + (m0 + c)*DIMC;
        const float* ar1 = ar0 + 16*DIMC;
        bf16x8 b0[6], b1[6];
        #pragma unroll
        for (int s = 0; s < 6; ++s){
            int k0 = s*32 + g*8;
            b0[s] = pack8(*(const float4*)(ar0 + k0), *(const float4*)(ar0 + k0 + 4));
            b1[s] = pack8(*(const float4*)(ar1 + k0), *(const float4*)(ar1 + k0 + 4));
        }
        #pragma unroll 2
        for (int j = 0; j < 12; ++j){
            float4 bb = *(const float4*)(sbias + j*16 + g*4);
            f32x4 a0 = {bb.x, bb.y, bb.z, bb.w};
            f32x4 a1 = a0;
            const bf16x8* wf = (const bf16x8*)wlds + (size_t)j*6*64 + l;
            #pragma unroll
            for (int s = 0; s < 6; ++s){
                bf16x8 wfr = wf[s*64];
                a0 = __builtin_amdgcn_mfma_f32_16x16x32_bf16(wfr, b0[s], a0, 0, 0, 0);
                a1 = __builtin_amdgcn_mfma_f32_16x16x32_bf16(wfr, b1[s], a1, 0, 0, 0);
            }
            int ncol = nc*192 + j*16 + g*4;
            size_t o0 = (m0 + c)*(size_t)N + ncol;
            size_t o1 = o0 + (size_t)16*N;
            if (outb){
                ushort4 u0, u1;
                u0.x=f2bf(a0[0]); u0.y=f2bf(a0[1]); u0.z=f2bf(a0[2]); u0.w=f2bf(a0[3]);
                u1.x=f2bf(a1[0]); u1.y=f2bf(a1[1]); u1.z=f2bf(a1[2]); u1.w=f2bf(a1[3]);
                *(ushort4*)(outb + o0) = u0;
                if (st1) *(ushort4*)(outb + o1) = u1;
            } else {
                float4 r0 = res ? *(const float4*)(res + o0) : make_float4(0.f,0.f,0.f,0.f);
                *(float4*)(out + o0) = make_float4(a0[0]+r0.x, a0[1]+r0.y, a0[2]+r0.z, a0[3]+r0.w);
                if (st1){
                    float4 r1 = res ? *(const float4*)(res + o1) : make_float4(0.f,0.f,0.f,0.f);
                    *(float4*)(out + o1) = make_float4(a1[0]+r1.x, a1[1]+r1.y, a1[2]+r1.z, a1[3]+r1.w);
                }
            }
        }
    }
}

// ---------------- fused MFMA MLP, T=2 token-tiles/wave, chunked hidden
// xout += gelu(xln@W1^T+b1)@W2^T+b2 ; 128 tokens/block
__global__ __launch_bounds__(256, 2) void mlp_mfma_kernel(
    const float* __restrict__ xln,
    const unsigned short* __restrict__ W1p, const float* __restrict__ b1,
    const unsigned short* __restrict__ W2p, const float* __restrict__ b2,
    float* __restrict__ xout)
{
    __shared__ __align__(16) unsigned short h[4][2][16][200];   // 51200 B, wave-private
    int l = threadIdx.x & 63, w = threadIdx.x >> 6;
    int c = l & 15, g = l >> 4;
    size_t m0 = (size_t)blockIdx.x*128 + w*16;
    size_t m1 = m0 + 64;
    const float* ar0 = xln + (m0 + c)*DIMC;
    const float* ar1 = xln + (m1 + c)*DIMC;
    bf16x8 bx0[6], bx1[6];
    #pragma unroll
    for (int s = 0; s < 6; ++s){
        int k0 = s*32 + g*8;
        bx0[s] = pack8(*(const float4*)(ar0 + k0), *(const float4*)(ar0 + k0 + 4));
        bx1[s] = pack8(*(const float4*)(ar1 + k0), *(const float4*)(ar1 + k0 + 4));
    }
    unsigned short* h0 = &h[w][0][c][0];
    unsigned short* h1 = &h[w][1][c][0];
    f32x4 acc[2][12];
    #pragma unroll
    for (int j = 0; j < 12; ++j){
        float4 b4 = *(const float4*)(b2 + j*16 + g*4);
        f32x4 v = {b4.x, b4.y, b4.z, b4.w};
        acc[0][j] = v; acc[1][j] = v;
    }
    for (int ch = 0; ch < 4; ++ch){
        // ---- fc1 + gelu for hidden features [ch*192, ch*192+192)
        #pragma unroll
        for (int jp = 0; jp < 6; ++jp){
            int j0 = ch*12 + 2*jp, j1 = j0 + 1;
            float4 b40 = *(const float4*)(b1 + j0*16 + g*4);
            float4 b41 = *(const float4*)(b1 + j1*16 + g*4);
            f32x4 p00 = {b40.x, b40.y, b40.z, b40.w}; f32x4 p10 = p00;
            f32x4 p01 = {b41.x, b41.y, b41.z, b41.w}; f32x4 p11 = p01;
            const bf16x8* wp0 = (const bf16x8*)(W1p + ((size_t)(j0*6)*64 + l)*8);
            const bf16x8* wp1 = (const bf16x8*)(W1p + ((size_t)(j1*6)*64 + l)*8);
            #pragma unroll
            for (int s = 0; s < 6; ++s){
                bf16x8 w0 = wp0[s*64], w1 = wp1[s*64];
                p00 = __builtin_amdgcn_mfma_f32_16x16x32_bf16(w0, bx0[s], p00, 0, 0, 0);
                p10 = __builtin_amdgcn_mfma_f32_16x16x32_bf16(w0, bx1[s], p10, 0, 0, 0);
                p01 = __builtin_amdgcn_mfma_f32_16x16x32_bf16(w1, bx0[s], p01, 0, 0, 0);
                p11 = __builtin_amdgcn_mfma_f32_16x16x32_bf16(w1, bx1[s], p11, 0, 0, 0);
            }
            ushort4 u;
            u.x=f2bf(gelu_f(p00[0])); u.y=f2bf(gelu_f(p00[1]));
            u.z=f2bf(gelu_f(p00[2])); u.w=f2bf(gelu_f(p00[3]));
            *(ushort4*)(h0 + (2*jp)*16 + g*4) = u;
            u.x=f2bf(gelu_f(p01[0])); u.y=f2bf(gelu_f(p01[1]));
            u.z=f2bf(gelu_f(p01[2])); u.w=f2bf(gelu_f(p01[3]));
            *(ushort4*)(h0 + (2*jp+1)*16 + g*4) = u;
            u.x=f2bf(gelu_f(p10[0])); u.y=f2bf(gelu_f(p10[1]));
            u.z=f2bf(gelu_f(p10[2])); u.w=f2bf(gelu_f(p10[3]));
            *(ushort4*)(h1 + (2*jp)*16 + g*4) = u;
            u.x=f2bf(gelu_f(p11[0])); u.y=f2bf(gelu_f(p11[1]));
            u.z=f2bf(gelu_f(p11[2])); u.w=f2bf(gelu_f(p11[3]));
            *(ushort4*)(h1 + (2*jp+1)*16 + g*4) = u;
        }
        // ---- fc2 partial over this k-chunk (wave-private rows: no barrier)
        #pragma unroll
        for (int s = 0; s < 6; ++s){
            bf16x8 a20 = *(const bf16x8*)(h0 + s*32 + g*8);
            bf16x8 a21 = *(const bf16x8*)(h1 + s*32 + g*8);
            #pragma unroll
            for (int j = 0; j < 12; ++j){
                bf16x8 wf = *(const bf16x8*)(W2p + ((size_t)(j*24 + ch*6 + s)*64 + l)*8);
                acc[0][j] = __builtin_amdgcn_mfma_f32_16x16x32_bf16(wf, a20, acc[0][j], 0, 0, 0);
                acc[1][j] = __builtin_amdgcn_mfma_f32_16x16x32_bf16(wf, a21, acc[1][j], 0, 0, 0);
            }
        }
    }
    #pragma unroll
    for (int j = 0; j < 12; ++j){
        size_t o0 = (m0 + c)*DIMC + j*16 + g*4;
        size_t o1 = (m1 + c)*DIMC + j*16 + g*4;
        float4 r0 = *(const float4*)(xout + o0);
        float4 r1 = *(const float4*)(xout + o1);
        *(float4*)(xout + o0) = make_float4(acc[0][j][0]+r0.x, acc[0][j][1]+r0.y,
                                            acc[0][j][2]+r0.z, acc[0][j][3]+r0.w);
        *(float4*)(xout + o1) = make_float4(acc[1][j][0]+r1.x, acc[1][j][1]+r1.y,
                                            acc[1][j][2]+r1.z, acc[1][j][3]+r1.w);
    }
}

// ---------------- attention core: one block per (window, head), fp16-dot2
__global__ __launch_bounds__(256) void attn_core_kernel(
    float* __restrict__ xio, const unsigned short* __restrict__ bufb,
    const float* __restrict__ qg, const float* __restrict__ rpb,
    int F, int qoff, int koff, int voff, int b0)
{
    __shared__ f16x2 qh[NTOK][17];
    __shared__ f16x2 kh[NTOK][17];
    __shared__ float sc[NTOK*NTOK];
    __shared__ f16x2 ph[NTOK][27];
    __shared__ f16x2 vt[HD][27];
    __shared__ unsigned short vlin[NTOK][34];
    __shared__ float sinv[NTOK];
    int blk = blockIdx.x;
    int hd  = blk % NHEADS;
    int wix = blk / NHEADS;
    int bloc = wix >> 4, win = wix & 15;
    int b = b0 + bloc;
    int wr = win >> 2, wc = win & 3;
    int tid = threadIdx.x;
    for (int i = tid; i < 3*784; i += 256){
        int which = i / 784, r = i - which*784;
        int t = r >> 4, d2 = r & 15;
        int h = wr*WSZ + t/WSZ, w = wc*WSZ + t - (t/WSZ)*WSZ;
        size_t row = (size_t)bloc*784 + h*RESX + w;
        if (which == 0){
            float f0, f1;
            if (qoff < 0){
                const float* qp = qg + ((size_t)b*NTOK + t)*DIMC + hd*HD + 2*d2;
                f0 = qp[0]; f1 = qp[1];
            } else {
                ushort2 u = *(const ushort2*)(bufb + row*F + qoff + hd*HD + 2*d2);
                f0 = bf2f(u.x); f1 = bf2f(u.y);
            }
            f16x2 qv; qv[0] = (_Float16)(f0*SCALE); qv[1] = (_Float16)(f1*SCALE);
            qh[t][d2] = qv;
        } else if (which == 1){
            ushort2 u = *(const ushort2*)(bufb + row*F + koff + hd*HD + 2*d2);
            f16x2 kv; kv[0] = (_Float16)bf2f(u.x); kv[1] = (_Float16)bf2f(u.y);
            kh[t][d2] = kv;
        } else {
            ushort2 u = *(const ushort2*)(bufb + row*F + voff + hd*HD + 2*d2);
            *(ushort2*)(&vlin[t][2*d2]) = u;
        }
    }
    __syncthreads();
    for (int i = tid; i < 2401 + 800; i += 256){
        if (i < 2401){
            int ti = i / NTOK, tj = i - (i/NTOK)*NTOK;
            int ri = ti/WSZ, ci = ti - ri*WSZ;
            int rj = tj/WSZ, cj = tj - rj*WSZ;
            float acc = rpb[((ri - rj + 6)*13 + (ci - cj + 6))*NHEADS + hd];
            #pragma unroll
            for (int dd = 0; dd < 16; ++dd)
                acc = fdot2(qh[ti][dd], kh[tj][dd], acc);
            sc[i] = acc;
        } else {
            int j = i - 2401;
            int d = j / 25, mm = j - (j/25)*25;
            float v0 = bf2f(vlin[2*mm][d]);
            float v1 = (2*mm + 1 < NTOK) ? bf2f(vlin[2*mm+1][d]) : 0.f;
            f16x2 vv; vv[0] = (_Float16)v0; vv[1] = (_Float16)v1;
            vt[d][mm] = vv;
        }
    }
    __syncthreads();
    for (int i = tid; i < 49*25; i += 256){
        int row = i / 25, mm = i - (i/25)*25;
        float e0 = __expf(sc[row*NTOK + 2*mm]);
        float e1 = (2*mm + 1 < NTOK) ? __expf(sc[row*NTOK + 2*mm + 1]) : 0.f;
        f16x2 pv; pv[0] = (_Float16)e0; pv[1] = (_Float16)e1;
        ph[row][mm] = pv;
    }
    __syncthreads();
    if (tid < 196){
        int row = tid >> 2, q0 = tid & 3;
        float s = 0.f;
        for (int mm = q0; mm < 25; mm += 4)
            s += (float)ph[row][mm][0] + (float)ph[row][mm][1];
        s += __shfl_xor(s, 1);
        s += __shfl_xor(s, 2);
        if (q0 == 0) sinv[row] = 1.0f / s;
    }
    __syncthreads();
    for (int i = tid; i < NTOK*HD; i += 256){
        int t = i >> 5, d = i & 31;
        float acc = 0.f;
        #pragma unroll
        for (int mm = 0; mm < 25; ++mm)
            acc = fdot2(ph[t][mm], vt[d][mm], acc);
        int h = wr*WSZ + t/WSZ, w = wc*WSZ + t - (t/WSZ)*WSZ;
        xio[(((size_t)b*RESX + h)*RESX + w)*DIMC + hd*HD + d] = acc * sinv[t];
    }
}

static inline int pick_ppw(int M){
    int ppw = M / 32768;
    if (ppw < 1) ppw = 1;
    if (ppw > 8) ppw = 8;
    return ppw;
}

extern "C" void kernel_launch(void* const* d_in, const int* in_sizes, int n_in,
                              void* d_out, int out_size, void* d_ws, size_t ws_size,
                              hipStream_t stream)
{
    (void)in_sizes; (void)n_in; (void)out_size;
    const float* x = (const float*)d_in[0];
    const float* fe_dw[2]  = {(const float*)d_in[1], (const float*)d_in[5]};
    const float* fe_se1[2] = {(const float*)d_in[2], (const float*)d_in[6]};
    const float* fe_se2[2] = {(const float*)d_in[3], (const float*)d_in[7]};
    const float* fe_pw[2]  = {(const float*)d_in[4], (const float*)d_in[8]};
    const float* n1g[2]  = {(const float*)d_in[9],  (const float*)d_in[22]};
    const float* n1b[2]  = {(const float*)d_in[10], (const float*)d_in[23]};
    const float* qkvw[2] = {(const float*)d_in[11], (const float*)d_in[24]};
    const float* qkvb[2] = {(const float*)d_in[12], (const float*)d_in[25]};
    const float* rpb[2]  = {(const float*)d_in[13], (const float*)d_in[26]};
    const float* prjw[2] = {(const float*)d_in[14], (const float*)d_in[27]};
    const float* prjb[2] = {(const float*)d_in[15], (const float*)d_in[28]};
    const float* n2g[2]  = {(const float*)d_in[16], (const float*)d_in[29]};
    const float* n2b[2]  = {(const float*)d_in[17], (const float*)d_in[30]};
    const float* fc1w[2] = {(const float*)d_in[18], (const float*)d_in[31]};
    const float* fc1b[2] = {(const float*)d_in[19], (const float*)d_in[32]};
    const float* fc2w[2] = {(const float*)d_in[20], (const float*)d_in[33]};
    const float* fc2b[2] = {(const float*)d_in[21], (const float*)d_in[34]};

    float* out = (float*)d_out;
    float* ws = (float*)d_ws;
    const size_t n28 = (size_t)NB*RESX*RESX*DIMC;     // 19,267,584
    const size_t n14 = (size_t)NB*14*14*DIMC;         //  4,816,896
    const size_t n7  = (size_t)NB*7*7*DIMC;           //  1,204,224
    float* region0 = ws;
    float* x7      = region0 + n28;
    float* s0      = x7 + n7;
    float* s1      = s0 + NB*DIMC;
    float* dyn     = s1 + NB*DIMC;       // phase A: x14 ; phase B: packed weights + qkv
    size_t fixedf  = n28 + n7 + 2ull*NB*DIMC;
    if (ws_size < (fixedf + n14) * sizeof(float)) return;
    size_t dynf = ws_size / sizeof(float) - fixedf;
    float* x14 = dyn;

    // packed-weight layout inside dyn (ushort elems)
    unsigned short* pk = (unsigned short*)dyn;
    const size_t PK_QKV0 = 0;                 // 576x192
    const size_t PK_QKV1 = PK_QKV0 + 576*192; // 384x192
    const size_t PK_PRJ0 = PK_QKV1 + 384*192;
    const size_t PK_PRJ1 = PK_PRJ0 + 192*192;
    const size_t PK_FC10 = PK_PRJ1 + 192*192;
    const size_t PK_FC11 = PK_FC10 + 768*192;
    const size_t PK_FC20 = PK_FC11 + 768*192;
    const size_t PK_FC21 = PK_FC20 + 192*768;
    const size_t PK_TOT  = PK_FC21 + 192*768; // 847,872 ushorts
    unsigned short* qkvbuf = pk + PK_TOT;
    size_t availu = 2*dynf - PK_TOT;          // ushort capacity for qkv buffer

    // ---- Phase A: GlobalQueryGen: 28 -> 14 -> 7 (f32; x14 lives in dyn)
    for (int fe = 0; fe < 2; ++fe){
        int H = fe ? 14 : 28;
        int HW = H * H;
        const float* src = fe ? x14 : x;
        float* dst = fe ? x7 : x14;
        dw_gelu_kernel<<<NB*HW, DIMC, 0, stream>>>(src, fe_dw[fe], region0, H, H);
        se_reduce_kernel<<<NB, DIMC, 0, stream>>>(region0, s0, HW);
        se_mlp_kernel<<<NB, DIMC, 0, stream>>>(s0, fe_se1[fe], fe_se2[fe], s1);
        gemm192_kernel<<<NB*HW/16, 256, 0, stream>>>(region0, fe_pw[fe], nullptr,
                                                     src, s1, HW, region0);
        maxpool_kernel<<<NB*(H/2)*(H/2), DIMC, 0, stream>>>(region0, dst, H, H);
    }

    // ---- pack weights to bf16 fragment order (overwrites x14 region; x14 dead now)
    pack_w_kernel<<<576*192/8/256, 256, 0, stream>>>(qkvw[0], pk + PK_QKV0, 192);
    pack_w_kernel<<<384*192/8/256, 256, 0, stream>>>(qkvw[1], pk + PK_QKV1, 192);
    pack_w_kernel<<<192*192/8/256, 256, 0, stream>>>(prjw[0], pk + PK_PRJ0, 192);
    pack_w_kernel<<<192*192/8/256, 256, 0, stream>>>(prjw[1], pk + PK_PRJ1, 192);
    pack_w_kernel<<<768*192/8/256, 256, 0, stream>>>(fc1w[0], pk + PK_FC10, 192);
    pack_w_kernel<<<768*192/8/256, 256, 0, stream>>>(fc1w[1], pk + PK_FC11, 192);
    pack_w_kernel<<<192*768/8/256, 256, 0, stream>>>(fc2w[0], pk + PK_FC20, 768);
    pack_w_kernel<<<192*768/8/256, 256, 0, stream>>>(fc2w[1], pk + PK_FC21, 768);

    // qkv chunking: multiples of 4 images
    int C = (int)(availu / (784ull * 576ull));
    C &= ~3;
    if (C > NB) C = NB;
    if (C < 4) return;

    // ---- Phase B: two attention blocks (0=local, 1=global query)
    for (int blk = 0; blk < 2; ++blk){
        const float* xin = blk ? (const float*)out : x;
        ln_kernel<<<TOK28/4, 256, 0, stream>>>(xin, n1g[blk], n1b[blk], region0);
        int F    = blk ? 384 : 576;
        int qoff = blk ? -1  : 0;
        int koff = blk ? 0   : 192;
        int voff = blk ? 192 : 384;
        const unsigned short* qp = pk + (blk ? PK_QKV1 : PK_QKV0);
        for (int b0 = 0; b0 < NB; b0 += C){
            int Ci = (NB - b0 < C) ? (NB - b0) : C;
            int M = Ci * 784;
            int ppw = pick_ppw(M);
            int tpb = 128 * ppw;
            dim3 gq((M + tpb - 1) / tpb, F / 192);
            const float* inp = region0 + (size_t)b0*784*DIMC;
            gemmW_kernel<<<gq, 256, 0, stream>>>(inp, qp, qkvb[blk],
                                                 nullptr, nullptr, qkvbuf, F, M, ppw);
            attn_core_kernel<<<Ci*16*NHEADS, 256, 0, stream>>>(
                region0, qkvbuf, blk ? x7 : nullptr, rpb[blk],
                F, qoff, koff, voff, b0);
        }
        {
            int M = TOK28;
            int ppw = pick_ppw(M);
            int tpb = 128 * ppw;
            dim3 gp((M + tpb - 1) / tpb, 1);
            gemmW_kernel<<<gp, 256, 0, stream>>>(region0,
                pk + (blk ? PK_PRJ1 : PK_PRJ0), prjb[blk], xin, out, nullptr,
                DIMC, M, ppw);
        }
        ln_kernel<<<TOK28/4, 256, 0, stream>>>(out, n2g[blk], n2b[blk], region0);
        mlp_mfma_kernel<<<TOK28/128, 256, 0, stream>>>(region0,
            pk + (blk ? PK_FC11 : PK_FC10), fc1b[blk],
            pk + (blk ? PK_FC21 : PK_FC20), fc2b[blk], out);
    }
}

// Round 6
// 1660.079 us; speedup vs baseline: 8.3813x; 1.3242x over previous
//
#include <hip/hip_runtime.h>
#include <hip/hip_bf16.h>
#include <math.h>

#define NB     128
#define RESX   28
#define DIMC   192
#define NHEADS 6
#define WSZ    7
#define HD     32
#define NTOK   49
#define SCALE  0.17677669529663687f   // 32^-0.5
#define TOK28  (NB*RESX*RESX)         // 100352

typedef short    bf16x8 __attribute__((ext_vector_type(8)));
typedef float    f32x4  __attribute__((ext_vector_type(4)));
typedef _Float16 f16x2  __attribute__((ext_vector_type(2)));

__device__ __forceinline__ float gelu_f(float x){
    return 0.5f * x * (1.0f + erff(x * 0.70710678118654752f));
}
__device__ __forceinline__ unsigned short f2bf(float f){
    unsigned int u = __float_as_uint(f);
    u += 0x7fffu + ((u >> 16) & 1u);          // RNE
    return (unsigned short)(u >> 16);
}
__device__ __forceinline__ float bf2f(unsigned short u){
    return __uint_as_float(((unsigned int)u) << 16);
}
__device__ __forceinline__ bf16x8 pack8(float4 u, float4 v){
    bf16x8 r;
    r[0]=(short)f2bf(u.x); r[1]=(short)f2bf(u.y); r[2]=(short)f2bf(u.z); r[3]=(short)f2bf(u.w);
    r[4]=(short)f2bf(v.x); r[5]=(short)f2bf(v.y); r[6]=(short)f2bf(v.z); r[7]=(short)f2bf(v.w);
    return r;
}
__device__ __forceinline__ float fdot2(f16x2 a, f16x2 b, float c){
#if __has_builtin(__builtin_amdgcn_fdot2)
    return __builtin_amdgcn_fdot2(a, b, c, false);
#else
    return c + (float)a[0]*(float)b[0] + (float)a[1]*(float)b[1];
#endif
}

// ---------------- LayerNorm: one wave per token (4 tokens / 256-thread block)
__global__ __launch_bounds__(256) void ln_kernel(const float* __restrict__ x,
        const float* __restrict__ g, const float* __restrict__ be,
        float* __restrict__ out)
{
    int wid = threadIdx.x >> 6, lane = threadIdx.x & 63;
    size_t tok = (size_t)blockIdx.x * 4 + wid;
    const float* xr = x + tok * DIMC;
    float v0 = xr[lane], v1 = xr[lane + 64], v2 = xr[lane + 128];
    float s  = v0 + v1 + v2;
    float sq = v0*v0 + v1*v1 + v2*v2;
    #pragma unroll
    for (int o = 32; o > 0; o >>= 1){ s += __shfl_xor(s, o); sq += __shfl_xor(sq, o); }
    float mean = s * (1.0f/DIMC);
    float var  = sq * (1.0f/DIMC) - mean*mean;
    float rstd = rsqrtf(var + 1e-5f);
    float* orow = out + tok * DIMC;
    orow[lane]     = (v0-mean)*rstd*g[lane]     + be[lane];
    orow[lane+64]  = (v1-mean)*rstd*g[lane+64]  + be[lane+64];
    orow[lane+128] = (v2-mean)*rstd*g[lane+128] + be[lane+128];
}

// ---------------- depthwise 3x3 (NHWC) + exact GELU
__global__ void dw_gelu_kernel(const float* __restrict__ x, const float* __restrict__ dw,
                               float* __restrict__ y, int H, int W)
{
    int p = blockIdx.x;
    int c = threadIdx.x;
    int w = p % W; int h = (p / W) % H; int b = p / (W*H);
    const float* base = x + (size_t)b*H*W*DIMC;
    float acc = 0.f;
    #pragma unroll
    for (int kh = 0; kh < 3; ++kh){
        int hh = h + kh - 1; if (hh < 0 || hh >= H) continue;
        #pragma unroll
        for (int kw = 0; kw < 3; ++kw){
            int ww = w + kw - 1; if (ww < 0 || ww >= W) continue;
            acc += base[((size_t)hh*W + ww)*DIMC + c] * dw[c*9 + kh*3 + kw];
        }
    }
    y[(size_t)p*DIMC + c] = gelu_f(acc);
}

// ---------------- SE: global average pool over HW
__global__ void se_reduce_kernel(const float* __restrict__ y, float* __restrict__ s0, int HW)
{
    int b = blockIdx.x; int c = threadIdx.x;
    const float* base = y + (size_t)b*HW*DIMC + c;
    float acc = 0.f;
    for (int p = 0; p < HW; ++p) acc += base[(size_t)p*DIMC];
    s0[b*DIMC + c] = acc / (float)HW;
}

// ---------------- SE: 192 -> gelu(48) -> sigmoid(192)
__global__ void se_mlp_kernel(const float* __restrict__ s0, const float* __restrict__ w1,
                              const float* __restrict__ w2, float* __restrict__ s)
{
    __shared__ float sl[DIMC];
    __shared__ float mid[48];
    int b = blockIdx.x; int t = threadIdx.x;
    sl[t] = s0[b*DIMC + t];
    __syncthreads();
    if (t < 48){
        float acc = 0.f;
        for (int c = 0; c < DIMC; ++c) acc += sl[c] * w1[t*DIMC + c];
        mid[t] = gelu_f(acc);
    }
    __syncthreads();
    float acc = 0.f;
    #pragma unroll 8
    for (int j = 0; j < 48; ++j) acc += mid[j] * w2[t*48 + j];
    s[b*DIMC + t] = 1.0f / (1.0f + expf(-acc));
}

// ---------------- maxpool 3x3 stride 2 pad 1 (NHWC)
__global__ void maxpool_kernel(const float* __restrict__ x, float* __restrict__ out,
                               int H, int W)
{
    int H2 = H >> 1, W2 = W >> 1;
    int p = blockIdx.x;
    int c = threadIdx.x;
    int w2 = p % W2; int h2 = (p / W2) % H2; int b = p / (W2*H2);
    float m = -INFINITY;
    #pragma unroll
    for (int dh = -1; dh <= 1; ++dh){
        int h = 2*h2 + dh; if (h < 0 || h >= H) continue;
        #pragma unroll
        for (int dw = -1; dw <= 1; ++dw){
            int w = 2*w2 + dw; if (w < 0 || w >= W) continue;
            m = fmaxf(m, x[(((size_t)b*H + h)*W + w)*DIMC + c]);
        }
    }
    out[(size_t)p*DIMC + c] = m;
}

// ---------------- weight pack: W[F][K] f32 -> fragment-ordered bf16
// frag (j = n-tile, s = k-step of 32): elem (lane,i) = W[j*16+(lane&15)][s*32+(lane>>4)*8+i]
__global__ __launch_bounds__(256) void pack_w_kernel(const float* __restrict__ W,
        unsigned short* __restrict__ out, int K)
{
    int t = blockIdx.x*256 + threadIdx.x;      // one thread = one (frag,lane) = 8 elems
    int lane = t & 63, frag = t >> 6;
    int ks = K >> 5;
    int j = frag / ks, s = frag - j*ks;
    const float* wr = W + (size_t)(j*16 + (lane & 15))*K + s*32 + ((lane>>4)<<3);
    float4 u = *(const float4*)wr;
    float4 v = *(const float4*)(wr + 4);
    bf16x8 r = pack8(u, v);
    *((bf16x8*)(out + (size_t)t*8)) = r;
}

// ---------------- weight-stationary MFMA GEMM (K=192, N=192-chunked in LDS)
// out[m][n] = bias?[n] + sum_k in[m][k]*(sv?[b][k])*W[n][k] (+res). f32 out.
__global__ __launch_bounds__(256) void gemmW_kernel(
    const float* __restrict__ in, const unsigned short* __restrict__ Wp,
    const float* __restrict__ bias, const float* __restrict__ res,
    float* __restrict__ out, int N, int M, int ppw,
    const float* __restrict__ sv, int HW)
{
    __shared__ __align__(16) unsigned short wlds[72*512];  // 72 frags = 73728 B
    __shared__ __align__(16) float sbias[192];
    int tid = threadIdx.x;
    int l = tid & 63, w = tid >> 6, c = l & 15, g = l >> 4;
    int nc = blockIdx.y;
    const bf16x8* wsrc = (const bf16x8*)(Wp + (size_t)nc*36864);
    bf16x8* wdst = (bf16x8*)wlds;
    #pragma unroll 2
    for (int i = tid; i < 4608; i += 256) wdst[i] = wsrc[i];
    if (tid < 48){
        float4 bb = bias ? ((const float4*)(bias + nc*192))[tid]
                         : make_float4(0.f,0.f,0.f,0.f);
        ((float4*)sbias)[tid] = bb;
    }
    __syncthreads();
    size_t mbase = (size_t)blockIdx.x*(128*ppw) + (size_t)w*(32*ppw);
    for (int p = 0; p < ppw; ++p){
        size_t m0 = mbase + (size_t)p*32;
        if ((long)m0 >= M) break;
        bool st1 = (long)(m0 + 16) < M;
        const float* ar0 = in + (m0 + c)*DIMC;
        const float* ar1 = ar0 + 16*DIMC;
        bf16x8 b0[6], b1[6];
        #pragma unroll
        for (int s = 0; s < 6; ++s){
            int k0 = s*32 + g*8;
            float4 u0 = *(const float4*)(ar0 + k0), v0 = *(const float4*)(ar0 + k0 + 4);
            float4 u1 = *(const float4*)(ar1 + k0), v1 = *(const float4*)(ar1 + k0 + 4);
            if (sv){
                int bi0 = (int)((m0 + c)/HW), bi1 = (int)((m0 + 16 + c)/HW);
                float4 a0 = *(const float4*)(sv + (size_t)bi0*DIMC + k0);
                float4 a1 = *(const float4*)(sv + (size_t)bi0*DIMC + k0 + 4);
                float4 d0 = *(const float4*)(sv + (size_t)bi1*DIMC + k0);
                float4 d1 = *(const float4*)(sv + (size_t)bi1*DIMC + k0 + 4);
                u0.x*=a0.x; u0.y*=a0.y; u0.z*=a0.z; u0.w*=a0.w;
                v0.x*=a1.x; v0.y*=a1.y; v0.z*=a1.z; v0.w*=a1.w;
                u1.x*=d0.x; u1.y*=d0.y; u1.z*=d0.z; u1.w*=d0.w;
                v1.x*=d1.x; v1.y*=d1.y; v1.z*=d1.z; v1.w*=d1.w;
            }
            b0[s] = pack8(u0, v0);
            b1[s] = pack8(u1, v1);
        }
        #pragma unroll 2
        for (int j = 0; j < 12; ++j){
            float4 bb = *(const float4*)(sbias + j*16 + g*4);
            f32x4 a0 = {bb.x, bb.y, bb.z, bb.w};
            f32x4 a1 = a0;
            const bf16x8* wf = (const bf16x8*)wlds + (size_t)j*6*64 + l;
            #pragma unroll
            for (int s = 0; s < 6; ++s){
                bf16x8 wfr = wf[s*64];
                a0 = __builtin_amdgcn_mfma_f32_16x16x32_bf16(wfr, b0[s], a0, 0, 0, 0);
                a1 = __builtin_amdgcn_mfma_f32_16x16x32_bf16(wfr, b1[s], a1, 0, 0, 0);
            }
            int ncol = nc*192 + j*16 + g*4;
            size_t o0 = (m0 + c)*(size_t)N + ncol;
            size_t o1 = o0 + (size_t)16*N;
            float4 r0 = res ? *(const float4*)(res + o0) : make_float4(0.f,0.f,0.f,0.f);
            *(float4*)(out + o0) = make_float4(a0[0]+r0.x, a0[1]+r0.y, a0[2]+r0.z, a0[3]+r0.w);
            if (st1){
                float4 r1 = res ? *(const float4*)(res + o1) : make_float4(0.f,0.f,0.f,0.f);
                *(float4*)(out + o1) = make_float4(a1[0]+r1.x, a1[1]+r1.y, a1[2]+r1.z, a1[3]+r1.w);
            }
        }
    }
}

// ---------------- fused MFMA MLP v3: wave-split n, T=4 m-tile reuse, h in shared LDS
// xout += gelu(xln@W1^T+b1)@W2^T+b2 ; 64 tokens/block, hidden chunks of 192
__global__ __launch_bounds__(256, 2) void mlp_mfma_kernel(
    const float* __restrict__ xln,
    const unsigned short* __restrict__ W1p, const float* __restrict__ b1,
    const unsigned short* __restrict__ W2p, const float* __restrict__ b2,
    float* __restrict__ xout)
{
    __shared__ __align__(16) unsigned short h[64*200];   // 25600 B
    int l = threadIdx.x & 63, w = threadIdx.x >> 6;
    int c = l & 15, g = l >> 4;
    size_t m0 = (size_t)blockIdx.x*64;
    bf16x8 bx[4][6];
    #pragma unroll
    for (int mt = 0; mt < 4; ++mt){
        const float* ar = xln + (m0 + mt*16 + c)*DIMC;
        #pragma unroll
        for (int s = 0; s < 6; ++s){
            int k0 = s*32 + g*8;
            bx[mt][s] = pack8(*(const float4*)(ar + k0), *(const float4*)(ar + k0 + 4));
        }
    }
    f32x4 acc[4][3];
    #pragma unroll
    for (int jj = 0; jj < 3; ++jj){
        float4 b4 = *(const float4*)(b2 + (3*w + jj)*16 + g*4);
        f32x4 v = {b4.x, b4.y, b4.z, b4.w};
        #pragma unroll
        for (int mt = 0; mt < 4; ++mt) acc[mt][jj] = v;
    }
    for (int ch = 0; ch < 4; ++ch){
        // ---- fc1: wave w owns hidden n-tiles ch*12 + 3w..3w+2
        #pragma unroll
        for (int jj = 0; jj < 3; ++jj){
            int j = ch*12 + 3*w + jj;
            float4 b40 = *(const float4*)(b1 + j*16 + g*4);
            f32x4 a0 = {b40.x, b40.y, b40.z, b40.w};
            f32x4 a1 = a0, a2 = a0, a3 = a0;
            const bf16x8* wp = (const bf16x8*)(W1p + ((size_t)(j*6)*64 + l)*8);
            #pragma unroll
            for (int s = 0; s < 6; ++s){
                bf16x8 wfr = wp[s*64];
                a0 = __builtin_amdgcn_mfma_f32_16x16x32_bf16(wfr, bx[0][s], a0, 0, 0, 0);
                a1 = __builtin_amdgcn_mfma_f32_16x16x32_bf16(wfr, bx[1][s], a1, 0, 0, 0);
                a2 = __builtin_amdgcn_mfma_f32_16x16x32_bf16(wfr, bx[2][s], a2, 0, 0, 0);
                a3 = __builtin_amdgcn_mfma_f32_16x16x32_bf16(wfr, bx[3][s], a3, 0, 0, 0);
            }
            int fb = (3*w + jj)*16 + g*4;
            ushort4 u;
            u.x=f2bf(gelu_f(a0[0])); u.y=f2bf(gelu_f(a0[1]));
            u.z=f2bf(gelu_f(a0[2])); u.w=f2bf(gelu_f(a0[3]));
            *(ushort4*)(h + (0*16 + c)*200 + fb) = u;
            u.x=f2bf(gelu_f(a1[0])); u.y=f2bf(gelu_f(a1[1]));
            u.z=f2bf(gelu_f(a1[2])); u.w=f2bf(gelu_f(a1[3]));
            *(ushort4*)(h + (1*16 + c)*200 + fb) = u;
            u.x=f2bf(gelu_f(a2[0])); u.y=f2bf(gelu_f(a2[1]));
            u.z=f2bf(gelu_f(a2[2])); u.w=f2bf(gelu_f(a2[3]));
            *(ushort4*)(h + (2*16 + c)*200 + fb) = u;
            u.x=f2bf(gelu_f(a3[0])); u.y=f2bf(gelu_f(a3[1]));
            u.z=f2bf(gelu_f(a3[2])); u.w=f2bf(gelu_f(a3[3]));
            *(ushort4*)(h + (3*16 + c)*200 + fb) = u;
        }
        __syncthreads();
        // ---- fc2 partial: wave w owns out n-tiles 3w..3w+2
        #pragma unroll
        for (int s = 0; s < 6; ++s){
            bf16x8 hf[4];
            #pragma unroll
            for (int mt = 0; mt < 4; ++mt)
                hf[mt] = *(const bf16x8*)(h + (mt*16 + c)*200 + s*32 + g*8);
            #pragma unroll
            for (int jj = 0; jj < 3; ++jj){
                int j = 3*w + jj;
                bf16x8 wf = *(const bf16x8*)(W2p + ((size_t)(j*24 + ch*6 + s)*64 + l)*8);
                #pragma unroll
                for (int mt = 0; mt < 4; ++mt)
                    acc[mt][jj] = __builtin_amdgcn_mfma_f32_16x16x32_bf16(wf, hf[mt], acc[mt][jj], 0, 0, 0);
            }
        }
        __syncthreads();
    }
    #pragma unroll
    for (int mt = 0; mt < 4; ++mt){
        #pragma unroll
        for (int jj = 0; jj < 3; ++jj){
            size_t o = (m0 + mt*16 + c)*DIMC + (3*w + jj)*16 + g*4;
            float4 r = *(const float4*)(xout + o);
            *(float4*)(xout + o) = make_float4(acc[mt][jj][0]+r.x, acc[mt][jj][1]+r.y,
                                               acc[mt][jj][2]+r.z, acc[mt][jj][3]+r.w);
        }
    }
}

// ---------------- fused qkv-MFMA + window attention: one block per (image, window)
// Phase 1: qkv = xln@W^T+b via MFMA -> LDS (q,k f16; v bf16). Then 6 heads:
// scores(+rel bias) -> exp -> rowsum -> PV, O written over xio.
__global__ __launch_bounds__(256, 2) void attn_fused_kernel(
    float* __restrict__ xio, const unsigned short* __restrict__ Wp,
    const float* __restrict__ bias, const float* __restrict__ qg,
    const float* __restrict__ rpb, int F)
{
    __shared__ f16x2 qh[NTOK*100];             // 19600 B (96 pairs + pad)
    __shared__ f16x2 kh[NTOK*100];             // 19600 B
    __shared__ unsigned short vb[NTOK*200];    // 19600 B (192 + pad)
    __shared__ float sc[NTOK*NTOK];            //  9604 B
    __shared__ f16x2 ph[NTOK*27];              //  5292 B
    __shared__ f16x2 vt[HD*27];                //  3456 B
    __shared__ float sinv[NTOK];
    int blk = blockIdx.x;
    int b = blk >> 4, win = blk & 15;
    int wr = win >> 2, wc = win & 3;
    int tid = threadIdx.x;
    int l = tid & 63, w4 = tid >> 6, c = l & 15, g = l >> 4;
    bool isglobal = (F == 384);
    // ---- phase 1: activation fragments (tokens of this window)
    bf16x8 bx[4][6];
    #pragma unroll
    for (int mt = 0; mt < 4; ++mt){
        int t = mt*16 + c;
        if (t < NTOK){
            int hh = wr*WSZ + t/WSZ, ww = wc*WSZ + t - (t/WSZ)*WSZ;
            const float* ar = xio + (((size_t)b*RESX + hh)*RESX + ww)*DIMC;
            #pragma unroll
            for (int s = 0; s < 6; ++s){
                int k0 = s*32 + g*8;
                bx[mt][s] = pack8(*(const float4*)(ar + k0), *(const float4*)(ar + k0 + 4));
            }
        } else {
            bf16x8 z = {0,0,0,0,0,0,0,0};
            #pragma unroll
            for (int s = 0; s < 6; ++s) bx[mt][s] = z;
        }
    }
    int NT = F >> 6;    // n-tiles per wave: 9 (local) / 6 (global)
    for (int q = 0; q < NT; ++q){
        int jn = w4*NT + q;
        float4 bb = *(const float4*)(bias + jn*16 + g*4);
        f32x4 a0 = {bb.x, bb.y, bb.z, bb.w};
        f32x4 a1 = a0, a2 = a0, a3 = a0;
        const bf16x8* wp = (const bf16x8*)(Wp + ((size_t)(jn*6)*64 + l)*8);
        #pragma unroll
        for (int s = 0; s < 6; ++s){
            bf16x8 wfr = wp[s*64];
            a0 = __builtin_amdgcn_mfma_f32_16x16x32_bf16(wfr, bx[0][s], a0, 0, 0, 0);
            a1 = __builtin_amdgcn_mfma_f32_16x16x32_bf16(wfr, bx[1][s], a1, 0, 0, 0);
            a2 = __builtin_amdgcn_mfma_f32_16x16x32_bf16(wfr, bx[2][s], a2, 0, 0, 0);
            a3 = __builtin_amdgcn_mfma_f32_16x16x32_bf16(wfr, bx[3][s], a3, 0, 0, 0);
        }
        int sect = jn / 12;
        int frel = (jn - sect*12)*16 + g*4;
        f32x4 av[4] = {a0, a1, a2, a3};
        #pragma unroll
        for (int mt = 0; mt < 4; ++mt){
            int t = mt*16 + c;
            if (t >= NTOK) continue;
            f32x4 a = av[mt];
            if (!isglobal && sect == 0){
                f16x2 p0, p1;
                p0[0]=(_Float16)(a[0]*SCALE); p0[1]=(_Float16)(a[1]*SCALE);
                p1[0]=(_Float16)(a[2]*SCALE); p1[1]=(_Float16)(a[3]*SCALE);
                qh[t*100 + (frel>>1)]     = p0;
                qh[t*100 + (frel>>1) + 1] = p1;
            } else if (sect == (isglobal ? 0 : 1)){
                f16x2 p0, p1;
                p0[0]=(_Float16)a[0]; p0[1]=(_Float16)a[1];
                p1[0]=(_Float16)a[2]; p1[1]=(_Float16)a[3];
                kh[t*100 + (frel>>1)]     = p0;
                kh[t*100 + (frel>>1) + 1] = p1;
            } else {
                ushort4 u;
                u.x=f2bf(a[0]); u.y=f2bf(a[1]); u.z=f2bf(a[2]); u.w=f2bf(a[3]);
                *(ushort4*)(vb + t*200 + frel) = u;
            }
        }
    }
    if (isglobal){
        for (int i = tid; i < NTOK*96; i += 256){
            int t = i / 96, d2 = i - (i/96)*96;
            const float* qp = qg + ((size_t)b*NTOK + t)*DIMC + 2*d2;
            f16x2 qv; qv[0] = (_Float16)(qp[0]*SCALE); qv[1] = (_Float16)(qp[1]*SCALE);
            qh[t*100 + d2] = qv;
        }
    }
    __syncthreads();
    // ---- per-head attention
    for (int hd = 0; hd < NHEADS; ++hd){
        for (int i = tid; i < 2401 + 800; i += 256){
            if (i < 2401){
                int ti = i / NTOK, tj = i - (i/NTOK)*NTOK;
                int ri = ti/WSZ, ci = ti - ri*WSZ;
                int rj = tj/WSZ, cj = tj - rj*WSZ;
                float acc = rpb[((ri - rj + 6)*13 + (ci - cj + 6))*NHEADS + hd];
                #pragma unroll
                for (int dd = 0; dd < 16; ++dd)
                    acc = fdot2(qh[ti*100 + hd*16 + dd], kh[tj*100 + hd*16 + dd], acc);
                sc[i] = acc;
            } else {
                int j = i - 2401;
                int d = j / 25, mm = j - (j/25)*25;
                float v0 = bf2f(vb[(2*mm)*200 + hd*32 + d]);
                float v1 = (2*mm + 1 < NTOK) ? bf2f(vb[(2*mm+1)*200 + hd*32 + d]) : 0.f;
                f16x2 vv; vv[0] = (_Float16)v0; vv[1] = (_Float16)v1;
                vt[d*27 + mm] = vv;
            }
        }
        __syncthreads();
        for (int i = tid; i < 49*25; i += 256){
            int row = i / 25, mm = i - (i/25)*25;
            float e0 = __expf(sc[row*NTOK + 2*mm]);
            float e1 = (2*mm + 1 < NTOK) ? __expf(sc[row*NTOK + 2*mm + 1]) : 0.f;
            f16x2 pv; pv[0] = (_Float16)e0; pv[1] = (_Float16)e1;
            ph[row*27 + mm] = pv;
        }
        __syncthreads();
        if (tid < 196){
            int row = tid >> 2, q0 = tid & 3;
            float s = 0.f;
            for (int mm = q0; mm < 25; mm += 4)
                s += (float)ph[row*27 + mm][0] + (float)ph[row*27 + mm][1];
            s += __shfl_xor(s, 1);
            s += __shfl_xor(s, 2);
            if (q0 == 0) sinv[row] = 1.0f / s;
        }
        __syncthreads();
        for (int i = tid; i < NTOK*HD; i += 256){
            int t = i >> 5, d = i & 31;
            float acc = 0.f;
            #pragma unroll
            for (int mm = 0; mm < 25; ++mm)
                acc = fdot2(ph[t*27 + mm], vt[d*27 + mm], acc);
            int hh = wr*WSZ + t/WSZ, ww = wc*WSZ + t - (t/WSZ)*WSZ;
            xio[(((size_t)b*RESX + hh)*RESX + ww)*DIMC + hd*HD + d] = acc * sinv[t];
        }
        __syncthreads();
    }
}

static inline int pick_ppw(int M){
    int ppw = M / 32768;
    if (ppw < 1) ppw = 1;
    if (ppw > 8) ppw = 8;
    return ppw;
}

extern "C" void kernel_launch(void* const* d_in, const int* in_sizes, int n_in,
                              void* d_out, int out_size, void* d_ws, size_t ws_size,
                              hipStream_t stream)
{
    (void)in_sizes; (void)n_in; (void)out_size;
    const float* x = (const float*)d_in[0];
    const float* fe_dw[2]  = {(const float*)d_in[1], (const float*)d_in[5]};
    const float* fe_se1[2] = {(const float*)d_in[2], (const float*)d_in[6]};
    const float* fe_se2[2] = {(const float*)d_in[3], (const float*)d_in[7]};
    const float* fe_pw[2]  = {(const float*)d_in[4], (const float*)d_in[8]};
    const float* n1g[2]  = {(const float*)d_in[9],  (const float*)d_in[22]};
    const float* n1b[2]  = {(const float*)d_in[10], (const float*)d_in[23]};
    const float* qkvw[2] = {(const float*)d_in[11], (const float*)d_in[24]};
    const float* qkvb[2] = {(const float*)d_in[12], (const float*)d_in[25]};
    const float* rpb[2]  = {(const float*)d_in[13], (const float*)d_in[26]};
    const float* prjw[2] = {(const float*)d_in[14], (const float*)d_in[27]};
    const float* prjb[2] = {(const float*)d_in[15], (const float*)d_in[28]};
    const float* n2g[2]  = {(const float*)d_in[16], (const float*)d_in[29]};
    const float* n2b[2]  = {(const float*)d_in[17], (const float*)d_in[30]};
    const float* fc1w[2] = {(const float*)d_in[18], (const float*)d_in[31]};
    const float* fc1b[2] = {(const float*)d_in[19], (const float*)d_in[32]};
    const float* fc2w[2] = {(const float*)d_in[20], (const float*)d_in[33]};
    const float* fc2b[2] = {(const float*)d_in[21], (const float*)d_in[34]};

    float* out = (float*)d_out;
    float* ws = (float*)d_ws;
    const size_t n28 = (size_t)NB*RESX*RESX*DIMC;     // 19,267,584
    const size_t n14 = (size_t)NB*14*14*DIMC;         //  4,816,896
    const size_t n7  = (size_t)NB*7*7*DIMC;           //  1,204,224
    float* region0 = ws;
    float* x7      = region0 + n28;
    float* s0      = x7 + n7;
    float* s1      = s0 + NB*DIMC;
    float* pwpk_f  = s1 + NB*DIMC;       // 2 packed pw weights: 73728 ushorts = 36864 f
    float* dyn     = pwpk_f + 36864;     // phase A: x14 ; phase B: packed weights
    size_t fixedf  = n28 + n7 + 2ull*NB*DIMC + 36864;
    if (ws_size < (fixedf + n14) * sizeof(float)) return;
    float* x14 = dyn;
    unsigned short* pwpk = (unsigned short*)pwpk_f;

    // packed-weight layout inside dyn (ushort elems), used in phase B only
    unsigned short* pk = (unsigned short*)dyn;
    const size_t PK_QKV0 = 0;                 // 576x192
    const size_t PK_QKV1 = PK_QKV0 + 576*192; // 384x192
    const size_t PK_PRJ0 = PK_QKV1 + 384*192;
    const size_t PK_PRJ1 = PK_PRJ0 + 192*192;
    const size_t PK_FC10 = PK_PRJ1 + 192*192;
    const size_t PK_FC11 = PK_FC10 + 768*192;
    const size_t PK_FC20 = PK_FC11 + 768*192;
    const size_t PK_FC21 = PK_FC20 + 192*768; // total 847872 ushorts < n14 floats

    // ---- pack pw weights (needed during phase A; live in fixed region)
    pack_w_kernel<<<192*192/8/256, 256, 0, stream>>>(fe_pw[0], pwpk, 192);
    pack_w_kernel<<<192*192/8/256, 256, 0, stream>>>(fe_pw[1], pwpk + 36864, 192);

    // ---- Phase A: GlobalQueryGen: 28 -> 14 -> 7
    for (int fe = 0; fe < 2; ++fe){
        int H = fe ? 14 : 28;
        int HW = H * H;
        int M = NB * HW;
        const float* src = fe ? x14 : x;
        float* dst = fe ? x7 : x14;
        dw_gelu_kernel<<<NB*HW, DIMC, 0, stream>>>(src, fe_dw[fe], region0, H, H);
        se_reduce_kernel<<<NB, DIMC, 0, stream>>>(region0, s0, HW);
        se_mlp_kernel<<<NB, DIMC, 0, stream>>>(s0, fe_se1[fe], fe_se2[fe], s1);
        int ppw = pick_ppw(M);
        dim3 ga((M + 128*ppw - 1) / (128*ppw), 1);
        gemmW_kernel<<<ga, 256, 0, stream>>>(region0, pwpk + fe*36864, nullptr,
                                             src, region0, DIMC, M, ppw, s1, HW);
        maxpool_kernel<<<NB*(H/2)*(H/2), DIMC, 0, stream>>>(region0, dst, H, H);
    }

    // ---- pack remaining weights (x14 dead now)
    pack_w_kernel<<<576*192/8/256, 256, 0, stream>>>(qkvw[0], pk + PK_QKV0, 192);
    pack_w_kernel<<<384*192/8/256, 256, 0, stream>>>(qkvw[1], pk + PK_QKV1, 192);
    pack_w_kernel<<<192*192/8/256, 256, 0, stream>>>(prjw[0], pk + PK_PRJ0, 192);
    pack_w_kernel<<<192*192/8/256, 256, 0, stream>>>(prjw[1], pk + PK_PRJ1, 192);
    pack_w_kernel<<<768*192/8/256, 256, 0, stream>>>(fc1w[0], pk + PK_FC10, 192);
    pack_w_kernel<<<768*192/8/256, 256, 0, stream>>>(fc1w[1], pk + PK_FC11, 192);
    pack_w_kernel<<<192*768/8/256, 256, 0, stream>>>(fc2w[0], pk + PK_FC20, 768);
    pack_w_kernel<<<192*768/8/256, 256, 0, stream>>>(fc2w[1], pk + PK_FC21, 768);

    // ---- Phase B: two attention blocks (0=local, 1=global query)
    for (int blk = 0; blk < 2; ++blk){
        const float* xin = blk ? (const float*)out : x;
        ln_kernel<<<TOK28/4, 256, 0, stream>>>(xin, n1g[blk], n1b[blk], region0);
        int F = blk ? 384 : 576;
        attn_fused_kernel<<<NB*16, 256, 0, stream>>>(
            region0, pk + (blk ? PK_QKV1 : PK_QKV0), qkvb[blk],
            blk ? x7 : nullptr, rpb[blk], F);
        {
            int M = TOK28;
            int ppw = pick_ppw(M);
            dim3 gp((M + 128*ppw - 1) / (128*ppw), 1);
            gemmW_kernel<<<gp, 256, 0, stream>>>(region0,
                pk + (blk ? PK_PRJ1 : PK_PRJ0), prjb[blk], xin, out,
                DIMC, M, ppw, nullptr, 0);
        }
        ln_kernel<<<TOK28/4, 256, 0, stream>>>(out, n2g[blk], n2b[blk], region0);
        mlp_mfma_kernel<<<TOK28/64, 256, 0, stream>>>(region0,
            pk + (blk ? PK_FC11 : PK_FC10), fc1b[blk],
            pk + (blk ? PK_FC21 : PK_FC20), fc2b[blk], out);
    }
}

// Round 7
// 1507.769 us; speedup vs baseline: 9.2280x; 1.1010x over previous
//
#include <hip/hip_runtime.h>
#include <hip/hip_bf16.h>
#include <math.h>

#define NB     128
#define RESX   28
#define DIMC   192
#define NHEADS 6
#define WSZ    7
#define HD     32
#define NTOK   49
#define SCALE  0.17677669529663687f   // 32^-0.5
#define TOK28  (NB*RESX*RESX)         // 100352
#define QSTR   208                    // ushorts per q/k row (192+16), 16B-aligned rows
#define VSTR   80                     // ushorts per vt row (64+16)
#define PSTR   80                     // ushorts per P row

typedef short    bf16x8 __attribute__((ext_vector_type(8)));
typedef float    f32x4  __attribute__((ext_vector_type(4)));

__device__ __forceinline__ float gelu_f(float x){
    return 0.5f * x * (1.0f + erff(x * 0.70710678118654752f));
}
__device__ __forceinline__ unsigned short f2bf(float f){
    unsigned int u = __float_as_uint(f);
    u += 0x7fffu + ((u >> 16) & 1u);          // RNE
    return (unsigned short)(u >> 16);
}
__device__ __forceinline__ float bf2f(unsigned short u){
    return __uint_as_float(((unsigned int)u) << 16);
}
__device__ __forceinline__ bf16x8 pack8(float4 u, float4 v){
    bf16x8 r;
    r[0]=(short)f2bf(u.x); r[1]=(short)f2bf(u.y); r[2]=(short)f2bf(u.z); r[3]=(short)f2bf(u.w);
    r[4]=(short)f2bf(v.x); r[5]=(short)f2bf(v.y); r[6]=(short)f2bf(v.z); r[7]=(short)f2bf(v.w);
    return r;
}

// ---------------- LayerNorm: one wave per token (4 tokens / 256-thread block)
__global__ __launch_bounds__(256) void ln_kernel(const float* __restrict__ x,
        const float* __restrict__ g, const float* __restrict__ be,
        float* __restrict__ out)
{
    int wid = threadIdx.x >> 6, lane = threadIdx.x & 63;
    size_t tok = (size_t)blockIdx.x * 4 + wid;
    const float* xr = x + tok * DIMC;
    float v0 = xr[lane], v1 = xr[lane + 64], v2 = xr[lane + 128];
    float s  = v0 + v1 + v2;
    float sq = v0*v0 + v1*v1 + v2*v2;
    #pragma unroll
    for (int o = 32; o > 0; o >>= 1){ s += __shfl_xor(s, o); sq += __shfl_xor(sq, o); }
    float mean = s * (1.0f/DIMC);
    float var  = sq * (1.0f/DIMC) - mean*mean;
    float rstd = rsqrtf(var + 1e-5f);
    float* orow = out + tok * DIMC;
    orow[lane]     = (v0-mean)*rstd*g[lane]     + be[lane];
    orow[lane+64]  = (v1-mean)*rstd*g[lane+64]  + be[lane+64];
    orow[lane+128] = (v2-mean)*rstd*g[lane+128] + be[lane+128];
}

// ---------------- depthwise 3x3 (NHWC) + exact GELU
__global__ void dw_gelu_kernel(const float* __restrict__ x, const float* __restrict__ dw,
                               float* __restrict__ y, int H, int W)
{
    int p = blockIdx.x;
    int c = threadIdx.x;
    int w = p % W; int h = (p / W) % H; int b = p / (W*H);
    const float* base = x + (size_t)b*H*W*DIMC;
    float acc = 0.f;
    #pragma unroll
    for (int kh = 0; kh < 3; ++kh){
        int hh = h + kh - 1; if (hh < 0 || hh >= H) continue;
        #pragma unroll
        for (int kw = 0; kw < 3; ++kw){
            int ww = w + kw - 1; if (ww < 0 || ww >= W) continue;
            acc += base[((size_t)hh*W + ww)*DIMC + c] * dw[c*9 + kh*3 + kw];
        }
    }
    y[(size_t)p*DIMC + c] = gelu_f(acc);
}

// ---------------- SE: global average pool over HW
__global__ void se_reduce_kernel(const float* __restrict__ y, float* __restrict__ s0, int HW)
{
    int b = blockIdx.x; int c = threadIdx.x;
    const float* base = y + (size_t)b*HW*DIMC + c;
    float acc = 0.f;
    for (int p = 0; p < HW; ++p) acc += base[(size_t)p*DIMC];
    s0[b*DIMC + c] = acc / (float)HW;
}

// ---------------- SE: 192 -> gelu(48) -> sigmoid(192)
__global__ void se_mlp_kernel(const float* __restrict__ s0, const float* __restrict__ w1,
                              const float* __restrict__ w2, float* __restrict__ s)
{
    __shared__ float sl[DIMC];
    __shared__ float mid[48];
    int b = blockIdx.x; int t = threadIdx.x;
    sl[t] = s0[b*DIMC + t];
    __syncthreads();
    if (t < 48){
        float acc = 0.f;
        for (int c = 0; c < DIMC; ++c) acc += sl[c] * w1[t*DIMC + c];
        mid[t] = gelu_f(acc);
    }
    __syncthreads();
    float acc = 0.f;
    #pragma unroll 8
    for (int j = 0; j < 48; ++j) acc += mid[j] * w2[t*48 + j];
    s[b*DIMC + t] = 1.0f / (1.0f + expf(-acc));
}

// ---------------- maxpool 3x3 stride 2 pad 1 (NHWC)
__global__ void maxpool_kernel(const float* __restrict__ x, float* __restrict__ out,
                               int H, int W)
{
    int H2 = H >> 1, W2 = W >> 1;
    int p = blockIdx.x;
    int c = threadIdx.x;
    int w2 = p % W2; int h2 = (p / W2) % H2; int b = p / (W2*H2);
    float m = -INFINITY;
    #pragma unroll
    for (int dh = -1; dh <= 1; ++dh){
        int h = 2*h2 + dh; if (h < 0 || h >= H) continue;
        #pragma unroll
        for (int dw = -1; dw <= 1; ++dw){
            int w = 2*w2 + dw; if (w < 0 || w >= W) continue;
            m = fmaxf(m, x[(((size_t)b*H + h)*W + w)*DIMC + c]);
        }
    }
    out[(size_t)p*DIMC + c] = m;
}

// ---------------- weight pack: W[F][K] f32 -> fragment-ordered bf16
__global__ __launch_bounds__(256) void pack_w_kernel(const float* __restrict__ W,
        unsigned short* __restrict__ out, int K)
{
    int t = blockIdx.x*256 + threadIdx.x;      // one thread = one (frag,lane) = 8 elems
    int lane = t & 63, frag = t >> 6;
    int ks = K >> 5;
    int j = frag / ks, s = frag - j*ks;
    const float* wr = W + (size_t)(j*16 + (lane & 15))*K + s*32 + ((lane>>4)<<3);
    float4 u = *(const float4*)wr;
    float4 v = *(const float4*)(wr + 4);
    bf16x8 r = pack8(u, v);
    *((bf16x8*)(out + (size_t)t*8)) = r;
}

// ---------------- weight-stationary MFMA GEMM (K=192, N=192-chunked in LDS)
__global__ __launch_bounds__(256) void gemmW_kernel(
    const float* __restrict__ in, const unsigned short* __restrict__ Wp,
    const float* __restrict__ bias, const float* __restrict__ res,
    float* __restrict__ out, int N, int M, int ppw,
    const float* __restrict__ sv, int HW)
{
    __shared__ __align__(16) unsigned short wlds[72*512];  // 72 frags = 73728 B
    __shared__ __align__(16) float sbias[192];
    int tid = threadIdx.x;
    int l = tid & 63, w = tid >> 6, c = l & 15, g = l >> 4;
    int nc = blockIdx.y;
    const bf16x8* wsrc = (const bf16x8*)(Wp + (size_t)nc*36864);
    bf16x8* wdst = (bf16x8*)wlds;
    #pragma unroll 2
    for (int i = tid; i < 4608; i += 256) wdst[i] = wsrc[i];
    if (tid < 48){
        float4 bb = bias ? ((const float4*)(bias + nc*192))[tid]
                         : make_float4(0.f,0.f,0.f,0.f);
        ((float4*)sbias)[tid] = bb;
    }
    __syncthreads();
    size_t mbase = (size_t)blockIdx.x*(128*ppw) + (size_t)w*(32*ppw);
    for (int p = 0; p < ppw; ++p){
        size_t m0 = mbase + (size_t)p*32;
        if ((long)m0 >= M) break;
        bool st1 = (long)(m0 + 16) < M;
        const float* ar0 = in + (m0 + c)*DIMC;
        const float* ar1 = ar0 + 16*DIMC;
        bf16x8 b0[6], b1[6];
        #pragma unroll
        for (int s = 0; s < 6; ++s){
            int k0 = s*32 + g*8;
            float4 u0 = *(const float4*)(ar0 + k0), v0 = *(const float4*)(ar0 + k0 + 4);
            float4 u1 = *(const float4*)(ar1 + k0), v1 = *(const float4*)(ar1 + k0 + 4);
            if (sv){
                int bi0 = (int)((m0 + c)/HW), bi1 = (int)((m0 + 16 + c)/HW);
                float4 a0 = *(const float4*)(sv + (size_t)bi0*DIMC + k0);
                float4 a1 = *(const float4*)(sv + (size_t)bi0*DIMC + k0 + 4);
                float4 d0 = *(const float4*)(sv + (size_t)bi1*DIMC + k0);
                float4 d1 = *(const float4*)(sv + (size_t)bi1*DIMC + k0 + 4);
                u0.x*=a0.x; u0.y*=a0.y; u0.z*=a0.z; u0.w*=a0.w;
                v0.x*=a1.x; v0.y*=a1.y; v0.z*=a1.z; v0.w*=a1.w;
                u1.x*=d0.x; u1.y*=d0.y; u1.z*=d0.z; u1.w*=d0.w;
                v1.x*=d1.x; v1.y*=d1.y; v1.z*=d1.z; v1.w*=d1.w;
            }
            b0[s] = pack8(u0, v0);
            b1[s] = pack8(u1, v1);
        }
        #pragma unroll 2
        for (int j = 0; j < 12; ++j){
            float4 bb = *(const float4*)(sbias + j*16 + g*4);
            f32x4 a0 = {bb.x, bb.y, bb.z, bb.w};
            f32x4 a1 = a0;
            const bf16x8* wf = (const bf16x8*)wlds + (size_t)j*6*64 + l;
            #pragma unroll
            for (int s = 0; s < 6; ++s){
                bf16x8 wfr = wf[s*64];
                a0 = __builtin_amdgcn_mfma_f32_16x16x32_bf16(wfr, b0[s], a0, 0, 0, 0);
                a1 = __builtin_amdgcn_mfma_f32_16x16x32_bf16(wfr, b1[s], a1, 0, 0, 0);
            }
            int ncol = nc*192 + j*16 + g*4;
            size_t o0 = (m0 + c)*(size_t)N + ncol;
            size_t o1 = o0 + (size_t)16*N;
            float4 r0 = res ? *(const float4*)(res + o0) : make_float4(0.f,0.f,0.f,0.f);
            *(float4*)(out + o0) = make_float4(a0[0]+r0.x, a0[1]+r0.y, a0[2]+r0.z, a0[3]+r0.w);
            if (st1){
                float4 r1 = res ? *(const float4*)(res + o1) : make_float4(0.f,0.f,0.f,0.f);
                *(float4*)(out + o1) = make_float4(a1[0]+r1.x, a1[1]+r1.y, a1[2]+r1.z, a1[3]+r1.w);
            }
        }
    }
}

// ---------------- fused MFMA MLP v3: wave-split n, T=4 m-tile reuse, h in shared LDS
__global__ __launch_bounds__(256, 2) void mlp_mfma_kernel(
    const float* __restrict__ xln,
    const unsigned short* __restrict__ W1p, const float* __restrict__ b1,
    const unsigned short* __restrict__ W2p, const float* __restrict__ b2,
    float* __restrict__ xout)
{
    __shared__ __align__(16) unsigned short h[64*200];   // 25600 B
    int l = threadIdx.x & 63, w = threadIdx.x >> 6;
    int c = l & 15, g = l >> 4;
    size_t m0 = (size_t)blockIdx.x*64;
    bf16x8 bx[4][6];
    #pragma unroll
    for (int mt = 0; mt < 4; ++mt){
        const float* ar = xln + (m0 + mt*16 + c)*DIMC;
        #pragma unroll
        for (int s = 0; s < 6; ++s){
            int k0 = s*32 + g*8;
            bx[mt][s] = pack8(*(const float4*)(ar + k0), *(const float4*)(ar + k0 + 4));
        }
    }
    f32x4 acc[4][3];
    #pragma unroll
    for (int jj = 0; jj < 3; ++jj){
        float4 b4 = *(const float4*)(b2 + (3*w + jj)*16 + g*4);
        f32x4 v = {b4.x, b4.y, b4.z, b4.w};
        #pragma unroll
        for (int mt = 0; mt < 4; ++mt) acc[mt][jj] = v;
    }
    for (int ch = 0; ch < 4; ++ch){
        #pragma unroll
        for (int jj = 0; jj < 3; ++jj){
            int j = ch*12 + 3*w + jj;
            float4 b40 = *(const float4*)(b1 + j*16 + g*4);
            f32x4 a0 = {b40.x, b40.y, b40.z, b40.w};
            f32x4 a1 = a0, a2 = a0, a3 = a0;
            const bf16x8* wp = (const bf16x8*)(W1p + ((size_t)(j*6)*64 + l)*8);
            #pragma unroll
            for (int s = 0; s < 6; ++s){
                bf16x8 wfr = wp[s*64];
                a0 = __builtin_amdgcn_mfma_f32_16x16x32_bf16(wfr, bx[0][s], a0, 0, 0, 0);
                a1 = __builtin_amdgcn_mfma_f32_16x16x32_bf16(wfr, bx[1][s], a1, 0, 0, 0);
                a2 = __builtin_amdgcn_mfma_f32_16x16x32_bf16(wfr, bx[2][s], a2, 0, 0, 0);
                a3 = __builtin_amdgcn_mfma_f32_16x16x32_bf16(wfr, bx[3][s], a3, 0, 0, 0);
            }
            int fb = (3*w + jj)*16 + g*4;
            ushort4 u;
            u.x=f2bf(gelu_f(a0[0])); u.y=f2bf(gelu_f(a0[1]));
            u.z=f2bf(gelu_f(a0[2])); u.w=f2bf(gelu_f(a0[3]));
            *(ushort4*)(h + (0*16 + c)*200 + fb) = u;
            u.x=f2bf(gelu_f(a1[0])); u.y=f2bf(gelu_f(a1[1]));
            u.z=f2bf(gelu_f(a1[2])); u.w=f2bf(gelu_f(a1[3]));
            *(ushort4*)(h + (1*16 + c)*200 + fb) = u;
            u.x=f2bf(gelu_f(a2[0])); u.y=f2bf(gelu_f(a2[1]));
            u.z=f2bf(gelu_f(a2[2])); u.w=f2bf(gelu_f(a2[3]));
            *(ushort4*)(h + (2*16 + c)*200 + fb) = u;
            u.x=f2bf(gelu_f(a3[0])); u.y=f2bf(gelu_f(a3[1]));
            u.z=f2bf(gelu_f(a3[2])); u.w=f2bf(gelu_f(a3[3]));
            *(ushort4*)(h + (3*16 + c)*200 + fb) = u;
        }
        __syncthreads();
        #pragma unroll
        for (int s = 0; s < 6; ++s){
            bf16x8 hf[4];
            #pragma unroll
            for (int mt = 0; mt < 4; ++mt)
                hf[mt] = *(const bf16x8*)(h + (mt*16 + c)*200 + s*32 + g*8);
            #pragma unroll
            for (int jj = 0; jj < 3; ++jj){
                int j = 3*w + jj;
                bf16x8 wf = *(const bf16x8*)(W2p + ((size_t)(j*24 + ch*6 + s)*64 + l)*8);
                #pragma unroll
                for (int mt = 0; mt < 4; ++mt)
                    acc[mt][jj] = __builtin_amdgcn_mfma_f32_16x16x32_bf16(wf, hf[mt], acc[mt][jj], 0, 0, 0);
            }
        }
        __syncthreads();
    }
    #pragma unroll
    for (int mt = 0; mt < 4; ++mt){
        #pragma unroll
        for (int jj = 0; jj < 3; ++jj){
            size_t o = (m0 + mt*16 + c)*DIMC + (3*w + jj)*16 + g*4;
            float4 r = *(const float4*)(xout + o);
            *(float4*)(xout + o) = make_float4(acc[mt][jj][0]+r.x, acc[mt][jj][1]+r.y,
                                               acc[mt][jj][2]+r.z, acc[mt][jj][3]+r.w);
        }
    }
}

// ---------------- fused qkv + window attention, all-MFMA. 512 threads, 1 block/window.
// Phase 1: qkv via MFMA -> LDS (q,k row-major bf16; v transposed). Then 24 units
// (4 q-tiles x 6 heads, 3/wave): S=mfma(q,k), bias+exp+rowsum in regs,
// P->LDS bf16, O^T = mfma(V^T, P^T) -> float4 stores over xio.
__global__ __launch_bounds__(512, 2) void attn_fused_kernel(
    float* __restrict__ xio, const unsigned short* __restrict__ Wp,
    const float* __restrict__ bias, const float* __restrict__ qg,
    const float* __restrict__ rpb, int F)
{
    __shared__ __align__(16) unsigned short q_lds[64*QSTR];  // 26624 B
    __shared__ __align__(16) unsigned short k_lds[64*QSTR];  // 26624 B
    __shared__ __align__(16) unsigned short vt[192*VSTR];    // 30720 B
    __shared__ __align__(16) unsigned short pp[8*16*PSTR];   // 20480 B
    __shared__ float sinv_l[8*16];
    __shared__ float rpb_l[NHEADS*169];
    int tid = threadIdx.x;
    int w8 = tid >> 6;
    int l = tid & 63, c = l & 15, g = l >> 4;
    int blk = blockIdx.x;
    int b = blk >> 4, win = blk & 15;
    int wr = win >> 2, wc = win & 3;
    bool isglobal = (F == 384);

    // zero pad token rows 49..63 of q,k and pad cols of vt
    for (int i = tid; i < 15*QSTR; i += 512){
        q_lds[49*QSTR + i] = 0; k_lds[49*QSTR + i] = 0;
    }
    for (int i = tid; i < 192*15; i += 512){
        int d = i / 15, t = 49 + (i - d*15);
        vt[d*VSTR + t] = 0;
    }
    for (int i = tid; i < NHEADS*169; i += 512){
        int hd = i / 169, r = i - hd*169;
        rpb_l[i] = rpb[r*NHEADS + hd];
    }

    // ---- phase 1: qkv projection via MFMA
    {
        bf16x8 bx[4][6];
        #pragma unroll
        for (int mt = 0; mt < 4; ++mt){
            int t = mt*16 + c;
            if (t < NTOK){
                int hh = wr*WSZ + t/WSZ, ww = wc*WSZ + t - (t/WSZ)*WSZ;
                const float* ar = xio + (((size_t)b*RESX + hh)*RESX + ww)*DIMC;
                #pragma unroll
                for (int s = 0; s < 6; ++s){
                    int k0 = s*32 + g*8;
                    bx[mt][s] = pack8(*(const float4*)(ar + k0), *(const float4*)(ar + k0 + 4));
                }
            } else {
                bf16x8 z = {0,0,0,0,0,0,0,0};
                #pragma unroll
                for (int s = 0; s < 6; ++s) bx[mt][s] = z;
            }
        }
        int ntile = F >> 4;    // 36 local / 24 global
        for (int jn = w8; jn < ntile; jn += 8){
            float4 bb4 = *(const float4*)(bias + jn*16 + g*4);
            f32x4 a0 = {bb4.x, bb4.y, bb4.z, bb4.w};
            f32x4 a1 = a0, a2 = a0, a3 = a0;
            const bf16x8* wp = (const bf16x8*)(Wp + ((size_t)(jn*6)*64 + l)*8);
            #pragma unroll
            for (int s = 0; s < 6; ++s){
                bf16x8 wfr = wp[s*64];
                a0 = __builtin_amdgcn_mfma_f32_16x16x32_bf16(wfr, bx[0][s], a0, 0, 0, 0);
                a1 = __builtin_amdgcn_mfma_f32_16x16x32_bf16(wfr, bx[1][s], a1, 0, 0, 0);
                a2 = __builtin_amdgcn_mfma_f32_16x16x32_bf16(wfr, bx[2][s], a2, 0, 0, 0);
                a3 = __builtin_amdgcn_mfma_f32_16x16x32_bf16(wfr, bx[3][s], a3, 0, 0, 0);
            }
            int sect = jn / 12 + (isglobal ? 1 : 0);   // 0=q,1=k,2=v
            int frel = (jn - (jn/12)*12)*16 + g*4;
            f32x4 av[4] = {a0, a1, a2, a3};
            #pragma unroll
            for (int mt = 0; mt < 4; ++mt){
                int t = mt*16 + c;
                if (t >= NTOK) continue;
                f32x4 a = av[mt];
                if (sect == 0){
                    ushort4 u;
                    u.x=f2bf(a[0]*SCALE); u.y=f2bf(a[1]*SCALE);
                    u.z=f2bf(a[2]*SCALE); u.w=f2bf(a[3]*SCALE);
                    *(ushort4*)(q_lds + t*QSTR + frel) = u;
                } else if (sect == 1){
                    ushort4 u;
                    u.x=f2bf(a[0]); u.y=f2bf(a[1]); u.z=f2bf(a[2]); u.w=f2bf(a[3]);
                    *(ushort4*)(k_lds + t*QSTR + frel) = u;
                } else {
                    vt[(frel+0)*VSTR + t] = f2bf(a[0]);
                    vt[(frel+1)*VSTR + t] = f2bf(a[1]);
                    vt[(frel+2)*VSTR + t] = f2bf(a[2]);
                    vt[(frel+3)*VSTR + t] = f2bf(a[3]);
                }
            }
        }
        if (isglobal){
            for (int i = tid; i < NTOK*48; i += 512){
                int t = i / 48, f4 = i - (i/48)*48;
                float4 qv = *(const float4*)(qg + ((size_t)b*NTOK + t)*DIMC + f4*4);
                ushort4 u;
                u.x=f2bf(qv.x*SCALE); u.y=f2bf(qv.y*SCALE);
                u.z=f2bf(qv.z*SCALE); u.w=f2bf(qv.w*SCALE);
                *(ushort4*)(q_lds + t*QSTR + f4*4) = u;
            }
        }
    }
    __syncthreads();

    // ---- 24 attention units, 3 per wave
    for (int uu = 0; uu < 3; ++uu){
        int unit = w8*3 + uu;
        int ti = unit / 6, hd = unit - (unit/6)*6;
        // S = q @ k^T (4 tiles over k-tokens)
        bf16x8 qa = *(const bf16x8*)(q_lds + (16*ti + c)*QSTR + hd*HD + g*8);
        f32x4 S[4];
        {
            const f32x4 z = {0.f, 0.f, 0.f, 0.f};
            #pragma unroll
            for (int tj = 0; tj < 4; ++tj){
                bf16x8 kb = *(const bf16x8*)(k_lds + (16*tj + c)*QSTR + hd*HD + g*8);
                S[tj] = __builtin_amdgcn_mfma_f32_16x16x32_bf16(qa, kb, z, 0, 0, 0);
            }
        }
        // bias + exp + pack + rowsum (rows i = 16ti+g*4+r, col j = 16tj+c)
        float tot[4] = {0.f, 0.f, 0.f, 0.f};
        unsigned short pu[4][4];
        int ibase = 16*ti + g*4;
        #pragma unroll
        for (int tj = 0; tj < 4; ++tj){
            int j = 16*tj + c;
            bool jok = (j < NTOK);
            int jc = jok ? j : 0;
            int rj = jc / 7, cj = jc - rj*7;
            #pragma unroll
            for (int r = 0; r < 4; ++r){
                int i = ibase + r;
                int ic = (i < NTOK) ? i : 0;
                int ri = ic / 7, ci = ic - ri*7;
                unsigned short u16 = 0;
                if (jok){
                    float bv = rpb_l[hd*169 + (ri - rj + 6)*13 + (ci - cj + 6)];
                    u16 = f2bf(__expf(S[tj][r] + bv));
                }
                pu[tj][r] = u16;
                tot[r] += bf2f(u16);
            }
        }
        #pragma unroll
        for (int r = 0; r < 4; ++r){
            float t0 = tot[r];
            t0 += __shfl_xor(t0, 1); t0 += __shfl_xor(t0, 2);
            t0 += __shfl_xor(t0, 4); t0 += __shfl_xor(t0, 8);
            tot[r] = t0;
        }
        if (c == 0){
            #pragma unroll
            for (int r = 0; r < 4; ++r)
                sinv_l[w8*16 + g*4 + r] = 1.0f / tot[r];
        }
        #pragma unroll
        for (int tj = 0; tj < 4; ++tj){
            #pragma unroll
            for (int r = 0; r < 4; ++r)
                pp[(w8*16 + g*4 + r)*PSTR + 16*tj + c] = pu[tj][r];
        }
        __syncthreads();
        // O^T = V^T @ P^T  (m = d, n = i, k = j)
        bf16x8 pb0 = *(const bf16x8*)(pp + (w8*16 + c)*PSTR + g*8);
        bf16x8 pb1 = *(const bf16x8*)(pp + (w8*16 + c)*PSTR + 32 + g*8);
        float si = sinv_l[w8*16 + c];
        int t = 16*ti + c;
        #pragma unroll
        for (int dm = 0; dm < 2; ++dm){
            int vrow = hd*HD + dm*16 + c;
            bf16x8 va0 = *(const bf16x8*)(vt + vrow*VSTR + g*8);
            bf16x8 va1 = *(const bf16x8*)(vt + vrow*VSTR + 32 + g*8);
            const f32x4 z = {0.f, 0.f, 0.f, 0.f};
            f32x4 o = __builtin_amdgcn_mfma_f32_16x16x32_bf16(va0, pb0, z, 0, 0, 0);
            o = __builtin_amdgcn_mfma_f32_16x16x32_bf16(va1, pb1, o, 0, 0, 0);
            if (t < NTOK){
                int hh = wr*WSZ + t/WSZ, ww = wc*WSZ + t - (t/WSZ)*WSZ;
                float4 ov = make_float4(o[0]*si, o[1]*si, o[2]*si, o[3]*si);
                *(float4*)(xio + (((size_t)b*RESX + hh)*RESX + ww)*DIMC
                           + hd*HD + dm*16 + g*4) = ov;
            }
        }
        __syncthreads();
    }
}

static inline int pick_ppw(int M){
    int ppw = M / 32768;
    if (ppw < 1) ppw = 1;
    if (ppw > 8) ppw = 8;
    return ppw;
}

extern "C" void kernel_launch(void* const* d_in, const int* in_sizes, int n_in,
                              void* d_out, int out_size, void* d_ws, size_t ws_size,
                              hipStream_t stream)
{
    (void)in_sizes; (void)n_in; (void)out_size;
    const float* x = (const float*)d_in[0];
    const float* fe_dw[2]  = {(const float*)d_in[1], (const float*)d_in[5]};
    const float* fe_se1[2] = {(const float*)d_in[2], (const float*)d_in[6]};
    const float* fe_se2[2] = {(const float*)d_in[3], (const float*)d_in[7]};
    const float* fe_pw[2]  = {(const float*)d_in[4], (const float*)d_in[8]};
    const float* n1g[2]  = {(const float*)d_in[9],  (const float*)d_in[22]};
    const float* n1b[2]  = {(const float*)d_in[10], (const float*)d_in[23]};
    const float* qkvw[2] = {(const float*)d_in[11], (const float*)d_in[24]};
    const float* qkvb[2] = {(const float*)d_in[12], (const float*)d_in[25]};
    const float* rpb[2]  = {(const float*)d_in[13], (const float*)d_in[26]};
    const float* prjw[2] = {(const float*)d_in[14], (const float*)d_in[27]};
    const float* prjb[2] = {(const float*)d_in[15], (const float*)d_in[28]};
    const float* n2g[2]  = {(const float*)d_in[16], (const float*)d_in[29]};
    const float* n2b[2]  = {(const float*)d_in[17], (const float*)d_in[30]};
    const float* fc1w[2] = {(const float*)d_in[18], (const float*)d_in[31]};
    const float* fc1b[2] = {(const float*)d_in[19], (const float*)d_in[32]};
    const float* fc2w[2] = {(const float*)d_in[20], (const float*)d_in[33]};
    const float* fc2b[2] = {(const float*)d_in[21], (const float*)d_in[34]};

    float* out = (float*)d_out;
    float* ws = (float*)d_ws;
    const size_t n28 = (size_t)NB*RESX*RESX*DIMC;     // 19,267,584
    const size_t n14 = (size_t)NB*14*14*DIMC;         //  4,816,896
    const size_t n7  = (size_t)NB*7*7*DIMC;           //  1,204,224
    float* region0 = ws;
    float* x7      = region0 + n28;
    float* s0      = x7 + n7;
    float* s1      = s0 + NB*DIMC;
    float* pwpk_f  = s1 + NB*DIMC;       // 2 packed pw weights: 73728 ushorts = 36864 f
    float* dyn     = pwpk_f + 36864;     // phase A: x14 ; phase B: packed weights
    size_t fixedf  = n28 + n7 + 2ull*NB*DIMC + 36864;
    if (ws_size < (fixedf + n14) * sizeof(float)) return;
    float* x14 = dyn;
    unsigned short* pwpk = (unsigned short*)pwpk_f;

    unsigned short* pk = (unsigned short*)dyn;
    const size_t PK_QKV0 = 0;                 // 576x192
    const size_t PK_QKV1 = PK_QKV0 + 576*192; // 384x192
    const size_t PK_PRJ0 = PK_QKV1 + 384*192;
    const size_t PK_PRJ1 = PK_PRJ0 + 192*192;
    const size_t PK_FC10 = PK_PRJ1 + 192*192;
    const size_t PK_FC11 = PK_FC10 + 768*192;
    const size_t PK_FC20 = PK_FC11 + 768*192;
    const size_t PK_FC21 = PK_FC20 + 192*768; // total 847872 ushorts < n14 floats

    // ---- pack pw weights (needed during phase A; live in fixed region)
    pack_w_kernel<<<192*192/8/256, 256, 0, stream>>>(fe_pw[0], pwpk, 192);
    pack_w_kernel<<<192*192/8/256, 256, 0, stream>>>(fe_pw[1], pwpk + 36864, 192);

    // ---- Phase A: GlobalQueryGen: 28 -> 14 -> 7
    for (int fe = 0; fe < 2; ++fe){
        int H = fe ? 14 : 28;
        int HW = H * H;
        int M = NB * HW;
        const float* src = fe ? x14 : x;
        float* dst = fe ? x7 : x14;
        dw_gelu_kernel<<<NB*HW, DIMC, 0, stream>>>(src, fe_dw[fe], region0, H, H);
        se_reduce_kernel<<<NB, DIMC, 0, stream>>>(region0, s0, HW);
        se_mlp_kernel<<<NB, DIMC, 0, stream>>>(s0, fe_se1[fe], fe_se2[fe], s1);
        int ppw = pick_ppw(M);
        dim3 ga((M + 128*ppw - 1) / (128*ppw), 1);
        gemmW_kernel<<<ga, 256, 0, stream>>>(region0, pwpk + fe*36864, nullptr,
                                             src, region0, DIMC, M, ppw, s1, HW);
        maxpool_kernel<<<NB*(H/2)*(H/2), DIMC, 0, stream>>>(region0, dst, H, H);
    }

    // ---- pack remaining weights (x14 dead now)
    pack_w_kernel<<<576*192/8/256, 256, 0, stream>>>(qkvw[0], pk + PK_QKV0, 192);
    pack_w_kernel<<<384*192/8/256, 256, 0, stream>>>(qkvw[1], pk + PK_QKV1, 192);
    pack_w_kernel<<<192*192/8/256, 256, 0, stream>>>(prjw[0], pk + PK_PRJ0, 192);
    pack_w_kernel<<<192*192/8/256, 256, 0, stream>>>(prjw[1], pk + PK_PRJ1, 192);
    pack_w_kernel<<<768*192/8/256, 256, 0, stream>>>(fc1w[0], pk + PK_FC10, 192);
    pack_w_kernel<<<768*192/8/256, 256, 0, stream>>>(fc1w[1], pk + PK_FC11, 192);
    pack_w_kernel<<<192*768/8/256, 256, 0, stream>>>(fc2w[0], pk + PK_FC20, 768);
    pack_w_kernel<<<192*768/8/256, 256, 0, stream>>>(fc2w[1], pk + PK_FC21, 768);

    // ---- Phase B: two attention blocks (0=local, 1=global query)
    for (int blk = 0; blk < 2; ++blk){
        const float* xin = blk ? (const float*)out : x;
        ln_kernel<<<TOK28/4, 256, 0, stream>>>(xin, n1g[blk], n1b[blk], region0);
        int F = blk ? 384 : 576;
        attn_fused_kernel<<<NB*16, 512, 0, stream>>>(
            region0, pk + (blk ? PK_QKV1 : PK_QKV0), qkvb[blk],
            blk ? x7 : nullptr, rpb[blk], F);
        {
            int M = TOK28;
            int ppw = pick_ppw(M);
            dim3 gp((M + 128*ppw - 1) / (128*ppw), 1);
            gemmW_kernel<<<gp, 256, 0, stream>>>(region0,
                pk + (blk ? PK_PRJ1 : PK_PRJ0), prjb[blk], xin, out,
                DIMC, M, ppw, nullptr, 0);
        }
        ln_kernel<<<TOK28/4, 256, 0, stream>>>(out, n2g[blk], n2b[blk], region0);
        mlp_mfma_kernel<<<TOK28/64, 256, 0, stream>>>(region0,
            pk + (blk ? PK_FC11 : PK_FC10), fc1b[blk],
            pk + (blk ? PK_FC21 : PK_FC20), fc2b[blk], out);
    }
}